// Round 1
// baseline (5438.034 us; speedup 1.0000x reference)
//
#include <hip/hip_runtime.h>
#include <cstddef>

#define HW 1024
#define NB 32
#define OT 16

__device__ __forceinline__ float elu1(float z){ return z > 0.f ? z : expm1f(z); }
__device__ __forceinline__ float sigm(float z){ return 1.f/(1.f+expf(-z)); }

// gm: 0 = concat(x[3],ul[160],b[6])  (169 ch)
//     1 = concat(ul[160],b[6])       (166 ch)
//     2 = ul only                    (160 ch)
__device__ __forceinline__ const float* src_ptr(const float* x, const float* ul, const float* b,
                                                int n, int c, int gm){
  if (gm == 0){
    if (c < 3)   return x  + ((size_t)n*3   + c)*HW;
    if (c < 163) return ul + ((size_t)n*160 + (c-3))*HW;
    return b + ((size_t)n*6 + (c-163))*HW;
  } else if (gm == 1){
    if (c < 160) return ul + ((size_t)n*160 + c)*HW;
    return b + ((size_t)n*6 + (c-160))*HW;
  }
  return ul + ((size_t)n*160 + c)*HW;
}

// SRCMODE: 0 plain buffer [N][Cin][HW]
//          1 concat_elu of buffer [N][Cin/2][HW]
//          2 concat_elu of gathered x_ul_b (Cin = 338)
//          3 concat_elu of gathered ul_b   (Cin = 332)
template<int SRCMODE>
__global__ __launch_bounds__(256) void k_gemm(const float* __restrict__ W, const float* __restrict__ bias,
    const float* __restrict__ in, const float* __restrict__ x, const float* __restrict__ ul,
    const float* __restrict__ b, float* __restrict__ out, int O, int Cin, int accflag){
  __shared__ float Ws[OT*352];
  const int n = blockIdx.z;
  const int o0 = blockIdx.y*OT;
  const int tid = threadIdx.x;
  for (int idx = tid; idx < OT*Cin; idx += 256){
    int o = idx / Cin, c = idx - o*Cin;
    Ws[c*OT + o] = (o0 + o < O) ? W[(size_t)(o0+o)*Cin + c] : 0.f;
  }
  __syncthreads();

  float a0[OT], a1[OT], a2[OT], a3[OT];
  #pragma unroll
  for (int i=0;i<OT;i++){ a0[i]=0.f; a1[i]=0.f; a2[i]=0.f; a3[i]=0.f; }

  const int Cb = Cin >> 1;
  for (int c = 0; c < Cin; ++c){
    float x0, x1, x2, x3;
    if (SRCMODE == 0){
      const float* p = in + ((size_t)n*Cin + c)*HW + tid;
      x0 = p[0]; x1 = p[256]; x2 = p[512]; x3 = p[768];
    } else {
      int base = (c < Cb) ? c : c - Cb;
      float sg = (c < Cb) ? 1.f : -1.f;
      const float* p;
      if (SRCMODE == 1)      p = in + ((size_t)n*Cb + base)*HW + tid;
      else if (SRCMODE == 2) p = src_ptr(x, ul, b, n, base, 0) + tid;
      else                   p = src_ptr(x, ul, b, n, base, 1) + tid;
      x0 = elu1(sg*p[0]); x1 = elu1(sg*p[256]); x2 = elu1(sg*p[512]); x3 = elu1(sg*p[768]);
    }
    const float* wr = &Ws[c*OT];
    #pragma unroll
    for (int i=0;i<OT;i++){
      float wv = wr[i];
      a0[i] += wv*x0; a1[i] += wv*x1; a2[i] += wv*x2; a3[i] += wv*x3;
    }
  }

  int nvalid = O - o0; if (nvalid > OT) nvalid = OT;
  for (int i = 0; i < nvalid; ++i){
    size_t ob = ((size_t)n*O + o0 + i)*HW + tid;
    float bs = bias[o0+i];
    if (accflag){
      out[ob]     += a0[i]+bs;
      out[ob+256] += a1[i]+bs;
      out[ob+512] += a2[i]+bs;
      out[ob+768] += a3[i]+bs;
    } else {
      out[ob]     = a0[i]+bs;
      out[ob+256] = a1[i]+bs;
      out[ob+512] = a2[i]+bs;
      out[ob+768] = a3[i]+bs;
    }
  }
}

// out[c] = src[c] + ga*sigmoid(gb), h2 = [N][2C][HW]
__global__ void k_res(const float* __restrict__ x, const float* __restrict__ ul, const float* __restrict__ b,
                      const float* __restrict__ h2, float* __restrict__ out, int C, int gm){
  int n = blockIdx.z, c = blockIdx.y;
  int p = blockIdx.x*256 + threadIdx.x;
  float v  = src_ptr(x, ul, b, n, c, gm)[p];
  float ga = h2[((size_t)n*2*C + c)*HW + p];
  float gb = h2[((size_t)n*2*C + C + c)*HW + p];
  out[((size_t)n*C + c)*HW + p] = v + ga*sigm(gb);
}

#define RT 8
#define KDIM 16
#define VDIM 80

__global__ __launch_bounds__(256) void k_attn(const float* __restrict__ Kb, const float* __restrict__ Qb,
    const float* __restrict__ Vb, float* __restrict__ out){
  __shared__ float s[RT][HW+1];       // 32.8 KB
  __shared__ float tile[VDIM*65];     // 20.8 KB (union: K tile 16x128 = 2048 floats fits)
  __shared__ float q[KDIM][RT];
  const int n  = blockIdx.y;
  const int rb = blockIdx.x*RT;
  const int tid = threadIdx.x;

  if (tid < KDIM*RT){
    int d = tid >> 3, r = tid & 7;
    q[d][r] = Qb[((size_t)n*KDIM + d)*HW + rb + r];
  }

  // phase 1: s[r][j] = sum_d q[d][r]*K[d][j]
  for (int jt = 0; jt < HW/128; ++jt){
    __syncthreads();
    for (int idx = tid; idx < KDIM*128; idx += 256){
      int d = idx >> 7, j = idx & 127;
      tile[d*128 + j] = Kb[((size_t)n*KDIM + d)*HW + jt*128 + j];
    }
    __syncthreads();
    #pragma unroll
    for (int k = 0; k < RT*128/256; ++k){
      int item = tid + k*256;
      int r = item >> 7, j = item & 127;
      float accv = 0.f;
      #pragma unroll
      for (int d = 0; d < KDIM; ++d) accv += q[d][r]*tile[d*128 + j];
      s[r][jt*128 + j] = accv;
    }
  }
  __syncthreads();

  // phase 2: faithful masked softmax per row
  {
    int r = tid >> 5, lane = tid & 31;
    int rg = rb + r;
    float m = 0.f;  // masked entries are exactly 0; always >=1 masked entry
    for (int j = lane; j < HW; j += 32)
      if (j < rg) m = fmaxf(m, s[r][j]);
    #pragma unroll
    for (int off = 16; off; off >>= 1) m = fmaxf(m, __shfl_xor(m, off, 32));
    float S = 0.f;
    for (int j = lane; j < HW; j += 32)
      if (j < rg) S += expf(s[r][j] - m);
    #pragma unroll
    for (int off = 16; off; off >>= 1) S += __shfl_xor(S, off, 32);
    float Z = S + (float)(HW - rg)*expf(-m);
    float inv = 1.f/(S + 1e-7f*Z);
    for (int j = lane; j < HW; j += 32)
      s[r][j] = (j < rg) ? expf(s[r][j] - m)*inv : 0.f;
  }

  // phase 3: PV, items = r*80+v (640 items over 256 threads, up to 3 each)
  const int i0 = tid, i1 = tid + 256, i2 = tid + 512;
  const int r_0 = i0/VDIM, v_0 = i0 - r_0*VDIM;
  const int r_1 = i1/VDIM, v_1 = i1 - r_1*VDIM;
  const bool has2 = (i2 < RT*VDIM);
  const int r_2 = has2 ? i2/VDIM : 0;
  const int v_2 = has2 ? (i2 - r_2*VDIM) : 0;
  float acc0 = 0.f, acc1 = 0.f, acc2 = 0.f;

  for (int jt = 0; jt < HW/64; ++jt){
    __syncthreads();
    for (int idx = tid; idx < VDIM*64; idx += 256){
      int v = idx >> 6, j = idx & 63;
      tile[v*65 + j] = Vb[((size_t)n*VDIM + v)*HW + jt*64 + j];
    }
    __syncthreads();
    #pragma unroll 8
    for (int j = 0; j < 64; ++j){
      float w0 = s[r_0][jt*64 + j];
      float w1 = s[r_1][jt*64 + j];
      float w2 = s[r_2][jt*64 + j];
      acc0 += w0*tile[v_0*65 + j];
      acc1 += w1*tile[v_1*65 + j];
      acc2 += w2*tile[v_2*65 + j];
    }
  }
  out[((size_t)n*VDIM + v_0)*HW + rb + r_0] = acc0;
  out[((size_t)n*VDIM + v_1)*HW + rb + r_1] = acc1;
  if (has2) out[((size_t)n*VDIM + v_2)*HW + rb + r_2] = acc2;
}

extern "C" void kernel_launch(void* const* d_in, const int* in_sizes, int n_in,
                              void* d_out, int out_size, void* d_ws, size_t ws_size,
                              hipStream_t stream) {
  const float* x    = (const float*)d_in[0];
  const float* ul   = (const float*)d_in[1];
  const float* bb   = (const float*)d_in[2];
  const float* gkWi = (const float*)d_in[3];  const float* gkbi = (const float*)d_in[4];
  const float* gkWo = (const float*)d_in[5];  const float* gkbo = (const float*)d_in[6];
  const float* gqWi = (const float*)d_in[7];  const float* gqbi = (const float*)d_in[8];
  const float* gqWo = (const float*)d_in[9];  const float* gqbo = (const float*)d_in[10];
  const float* gvWi = (const float*)d_in[11]; const float* gvbi = (const float*)d_in[12];
  const float* gvWo = (const float*)d_in[13]; const float* gvbo = (const float*)d_in[14];
  const float* nkW  = (const float*)d_in[15]; const float* nkb  = (const float*)d_in[16];
  const float* nqW  = (const float*)d_in[17]; const float* nqb  = (const float*)d_in[18];
  const float* nvW  = (const float*)d_in[19]; const float* nvb  = (const float*)d_in[20];
  const float* goWi = (const float*)d_in[21]; const float* gobi = (const float*)d_in[22];
  const float* goWs = (const float*)d_in[23]; const float* gobs = (const float*)d_in[24];
  const float* goWo = (const float*)d_in[25]; const float* gobo = (const float*)d_in[26];
  float* outp = (float*)d_out;
  float* ws   = (float*)d_ws;

  // workspace layout (floats)
  size_t offC = 0;                                  // h1 buffer, up to 169 ch
  size_t offE = offC + (size_t)NB*169*HW;           // h2 buffer, up to 338 ch
  size_t offF = offE + (size_t)NB*338*HW;           // grn out,  up to 169 ch
  size_t offG = offF + (size_t)NB*169*HW;           // keys    [32][16][1024]
  size_t offH = offG + (size_t)NB*16*HW;            // queries [32][16][1024]
  size_t offI = offH + (size_t)NB*16*HW;            // values  [32][80][1024]
  size_t offJ = offI + (size_t)NB*80*HW;            // att_v   [32][80][1024]
  float *C = ws+offC, *E = ws+offE, *F = ws+offF, *G = ws+offG, *H = ws+offH, *I = ws+offI, *J = ws+offJ;

  dim3 blk(256);
  auto tiles = [](int O){ return (O + OT - 1)/OT; };

  // ---- keys path: grn(x_ul_b) -> nin(nkW) ----
  k_gemm<2><<<dim3(1,tiles(169),NB), blk, 0, stream>>>(gkWi, gkbi, nullptr, x, ul, bb, C, 169, 338, 0);
  k_gemm<1><<<dim3(1,tiles(338),NB), blk, 0, stream>>>(gkWo, gkbo, C, x, ul, bb, E, 338, 338, 0);
  k_res<<<dim3(4,169,NB), blk, 0, stream>>>(x, ul, bb, E, F, 169, 0);
  k_gemm<0><<<dim3(1,1,NB), blk, 0, stream>>>(nkW, nkb, F, x, ul, bb, G, 16, 169, 0);

  // ---- queries path: grn(ul_b) -> nin(nqW) ----
  k_gemm<3><<<dim3(1,tiles(166),NB), blk, 0, stream>>>(gqWi, gqbi, nullptr, x, ul, bb, C, 166, 332, 0);
  k_gemm<1><<<dim3(1,tiles(332),NB), blk, 0, stream>>>(gqWo, gqbo, C, x, ul, bb, E, 332, 332, 0);
  k_res<<<dim3(4,166,NB), blk, 0, stream>>>(x, ul, bb, E, F, 166, 1);
  k_gemm<0><<<dim3(1,1,NB), blk, 0, stream>>>(nqW, nqb, F, x, ul, bb, H, 16, 166, 0);

  // ---- values path: grn(x_ul_b) -> nin(nvW) ----
  k_gemm<2><<<dim3(1,tiles(169),NB), blk, 0, stream>>>(gvWi, gvbi, nullptr, x, ul, bb, C, 169, 338, 0);
  k_gemm<1><<<dim3(1,tiles(338),NB), blk, 0, stream>>>(gvWo, gvbo, C, x, ul, bb, E, 338, 338, 0);
  k_res<<<dim3(4,169,NB), blk, 0, stream>>>(x, ul, bb, E, F, 169, 0);
  k_gemm<0><<<dim3(1,tiles(80),NB), blk, 0, stream>>>(nvW, nvb, F, x, ul, bb, I, 80, 169, 0);

  // ---- attention ----
  k_attn<<<dim3(HW/RT, NB), blk, 0, stream>>>(G, H, I, J);

  // ---- output grn: ul with aux att_v ----
  k_gemm<1><<<dim3(1,tiles(160),NB), blk, 0, stream>>>(goWi, gobi, ul, x, ul, bb, C, 160, 320, 0);
  k_gemm<1><<<dim3(1,tiles(160),NB), blk, 0, stream>>>(goWs, gobs, J, x, ul, bb, C, 160, 160, 1);
  k_gemm<1><<<dim3(1,tiles(320),NB), blk, 0, stream>>>(goWo, gobo, C, x, ul, bb, E, 320, 320, 0);
  k_res<<<dim3(4,160,NB), blk, 0, stream>>>(x, ul, bb, E, outp, 160, 2);
}

// Round 2
// 2156.646 us; speedup vs baseline: 2.5215x; 2.5215x over previous
//
#include <hip/hip_runtime.h>
#include <cstddef>
#include <cstdint>

#define HW 1024
#define NBATCH 32

typedef unsigned short ushort_t;
typedef unsigned int uint_t;
typedef short s16x8 __attribute__((ext_vector_type(8)));
typedef float f32x4 __attribute__((ext_vector_type(4)));

__device__ __forceinline__ float elu1(float z){ return z > 0.f ? z : expm1f(z); }
__device__ __forceinline__ float sigm(float z){ return 1.f/(1.f+expf(-z)); }
__device__ __forceinline__ ushort_t f2bf(float f){
  uint_t u = __builtin_bit_cast(uint_t, f);
  u += 0x7FFFu + ((u >> 16) & 1u);          // RNE (finite values only)
  return (ushort_t)(u >> 16);
}
__device__ __forceinline__ float bf2f(ushort_t h){
  uint_t u = ((uint_t)h) << 16;
  return __builtin_bit_cast(float, u);
}

__device__ __forceinline__ void gload_lds16(const void* g, void* l){
  __builtin_amdgcn_global_load_lds((const __attribute__((address_space(1))) unsigned int*)g,
                                   (__attribute__((address_space(3))) unsigned int*)l, 16, 0, 0);
}

// gm: 0 = concat(x[3],ul[160],b[6]) (169 ch), 1 = concat(ul,b) (166), 2 = ul (160)
__device__ __forceinline__ const float* src_ptr(const float* x, const float* ul, const float* b,
                                                int n, int c, int gm){
  if (gm == 0){
    if (c < 3)   return x  + ((size_t)n*3   + c)*HW;
    if (c < 163) return ul + ((size_t)n*160 + (c-3))*HW;
    return b + ((size_t)n*6 + (c-163))*HW;
  } else if (gm == 1){
    if (c < 160) return ul + ((size_t)n*160 + c)*HW;
    return b + ((size_t)n*6 + (c-160))*HW;
  }
  return ul + ((size_t)n*160 + c)*HW;
}

// ---------------- concat_elu -> bf16 pixel-major act buffer ----------------
// out[px][ch], ch in [0,P1) = elu(src), [P1, P1+Cb) = elu(-src); CP = row stride
// GM 0/1/2: channel-major fp32 gather; GM 3: att_v pixel-major fp32 (stride 80)
template<int GM>
__global__ void k_act(const float* __restrict__ x, const float* __restrict__ ul,
                      const float* __restrict__ b, const float* __restrict__ av,
                      ushort_t* __restrict__ out, int Cb, int P1, int CP){
  int pxg = blockIdx.x*256 + threadIdx.x;     // 0..32767
  int n = pxg >> 10, hw = pxg & 1023;
  ushort_t* orow = out + (size_t)pxg * CP;
  for (int c8 = 0; c8 < P1; c8 += 8){
    ushort_t pbuf[8], nbuf[8];
    #pragma unroll
    for (int j = 0; j < 8; ++j){
      int c = c8 + j;
      float s = 0.f;
      if (c < Cb){
        if (GM == 3) s = av[(size_t)pxg*80 + c];
        else         s = src_ptr(x, ul, b, n, c, GM)[hw];
      }
      pbuf[j] = f2bf(elu1(s));
      nbuf[j] = f2bf(elu1(-s));
    }
    uint4 up, un;
    up.x = (uint_t)pbuf[0] | ((uint_t)pbuf[1]<<16);
    up.y = (uint_t)pbuf[2] | ((uint_t)pbuf[3]<<16);
    up.z = (uint_t)pbuf[4] | ((uint_t)pbuf[5]<<16);
    up.w = (uint_t)pbuf[6] | ((uint_t)pbuf[7]<<16);
    un.x = (uint_t)nbuf[0] | ((uint_t)nbuf[1]<<16);
    un.y = (uint_t)nbuf[2] | ((uint_t)nbuf[3]<<16);
    un.z = (uint_t)nbuf[4] | ((uint_t)nbuf[5]<<16);
    un.w = (uint_t)nbuf[6] | ((uint_t)nbuf[7]<<16);
    *(uint4*)(orow + c8)      = up;
    *(uint4*)(orow + P1 + c8) = un;
  }
}

// ---------------- grn residual: out = src + ga*sigmoid(gb) ----------------
// h2 bf16 pixel-major stride OPh (ga=ch c, gb=ch C+c). FINAL: fp32 channel-major out.
template<int FINAL>
__global__ void k_res2(const float* __restrict__ x, const float* __restrict__ ul,
                       const float* __restrict__ b, const ushort_t* __restrict__ h2,
                       void* __restrict__ outv, int C, int OPh, int P1g, int gm){
  int pxg = blockIdx.x*256 + threadIdx.x;
  int n = pxg >> 10, hw = pxg & 1023;
  const ushort_t* hrow = h2 + (size_t)pxg*OPh;
  const int lim = FINAL ? C : P1g;
  for (int c8 = 0; c8 < lim; c8 += 8){
    ushort_t buf[8];
    #pragma unroll
    for (int j = 0; j < 8; ++j){
      int c = c8 + j;
      float r = 0.f;
      if (c < C){
        float ga = bf2f(hrow[c]);
        float gb = bf2f(hrow[C + c]);
        float s  = src_ptr(x, ul, b, n, c, gm)[hw];
        r = s + ga*sigm(gb);
      }
      if (FINAL){ if (c < C) ((float*)outv)[((size_t)n*C + c)*HW + hw] = r; }
      else buf[j] = f2bf(r);
    }
    if (!FINAL){
      uint4 u;
      u.x = (uint_t)buf[0] | ((uint_t)buf[1]<<16);
      u.y = (uint_t)buf[2] | ((uint_t)buf[3]<<16);
      u.z = (uint_t)buf[4] | ((uint_t)buf[5]<<16);
      u.w = (uint_t)buf[6] | ((uint_t)buf[7]<<16);
      *(uint4*)((ushort_t*)outv + (size_t)pxg*P1g + c8) = u;
    }
  }
}

// ---------------- MFMA GEMM: out[o,px] = sum_k W[o,k]*act[px,k] + bias ----------------
// act: bf16 pixel-major, row stride CP (16B multiple). Weight col for act-ch kk:
//   kk<K1 -> kk ; P1<=kk<P1+K2 -> K1+kk-P1 ; else zero.  Kpad = ceil-32 K-loop bound.
// EPI: 0 = fp32 pixel-major (stride OP); 1 = bf16 pixel-major; 2 = concat_elu bf16
//      (pos at ch, neg at P1o+ch, stride OP); 3 = like 2 but adds accin fp32 (stride AST).
#define STAGE_B(bufi, ktv) do { \
    int c0_ = (ktv)*32; \
    ushort_t* dstb_ = Blds + (bufi)*8192; \
    _Pragma("unroll") \
    for (int i_ = 0; i_ < 4; ++i_){ \
      int px_ = (w*4 + i_)*16 + (l>>2); \
      const ushort_t* gsrc_ = actn + (size_t)px_*CP + c0_ + (l&3)*8; \
      gload_lds16(gsrc_, dstb_ + (w*4 + i_)*512); \
    } \
  } while(0)

template<int EPI>
__global__ __launch_bounds__(256) void k_gmm(const float* __restrict__ W, const float* __restrict__ bias,
    const ushort_t* __restrict__ act, const float* __restrict__ accin, void* __restrict__ outv,
    int O, int Ktot, int K1, int P1, int CP, int Kpad, int OP, int P1o, int AST)
{
  extern __shared__ ushort_t smem[];
  const int AR = Kpad + 8;                 // padded A row stride (bank spread)
  ushort_t* Alds = smem;                   // [32][AR]
  ushort_t* Blds = smem + 32*AR;           // 2 x [256][32]
  const int tid = threadIdx.x;
  const int w = tid >> 6, l = tid & 63;
  const int n = blockIdx.x >> 2, hw0 = (blockIdx.x & 3)*256;
  const int o0 = blockIdx.y*32;
  const int K2 = Ktot - K1;

  // stage A (weights, fp32 -> bf16, channel-gap mapping, zero pad)
  for (int r = 0; r < 32; ++r){
    int o = o0 + r;
    const float* Wr = W + (size_t)o*Ktot;
    for (int kk = tid; kk < Kpad; kk += 256){
      int k = (kk < K1) ? kk : ((kk >= P1 && kk < P1 + K2) ? (K1 + kk - P1) : -1);
      float v = (o < O && k >= 0) ? Wr[k] : 0.f;
      Alds[r*AR + kk] = f2bf(v);
    }
  }

  const ushort_t* actn = act + (size_t)(n*HW + hw0)*CP;
  f32x4 acc[2][4];
  #pragma unroll
  for (int s = 0; s < 2; ++s)
    #pragma unroll
    for (int t = 0; t < 4; ++t) acc[s][t] = (f32x4){0.f,0.f,0.f,0.f};

  const int NT = Kpad >> 5;
  STAGE_B(0, 0);
  __syncthreads();

  for (int kt = 0; kt < NT; ++kt){
    int cur = kt & 1;
    if (kt + 1 < NT) STAGE_B(cur^1, kt+1);
    int ka = kt*32 + (l>>4)*8;
    s16x8 a0 = *(const s16x8*)(Alds + (l&15)*AR + ka);
    s16x8 a1 = *(const s16x8*)(Alds + ((l&15)+16)*AR + ka);
    const ushort_t* Bb = Blds + cur*8192 + (w*64 + (l&15))*32 + (l>>4)*8;
    #pragma unroll
    for (int t = 0; t < 4; ++t){
      s16x8 bv = *(const s16x8*)(Bb + t*512);
      acc[0][t] = __builtin_amdgcn_mfma_f32_16x16x32_bf16(a0, bv, acc[0][t], 0, 0, 0);
      acc[1][t] = __builtin_amdgcn_mfma_f32_16x16x32_bf16(a1, bv, acc[1][t], 0, 0, 0);
    }
    __syncthreads();
  }

  // epilogue: D frag: col = l&15 (px), row = (l>>4)*4 + reg (channel)
  const int g = l >> 4, cc = l & 15;
  #pragma unroll
  for (int s = 0; s < 2; ++s){
    int ch = o0 + s*16 + g*4;
    if (ch >= O) continue;
    float b0 = bias[ch];
    float b1 = (ch+1 < O) ? bias[ch+1] : 0.f;
    float b2 = (ch+2 < O) ? bias[ch+2] : 0.f;
    float b3 = (ch+3 < O) ? bias[ch+3] : 0.f;
    #pragma unroll
    for (int t = 0; t < 4; ++t){
      size_t pb = (size_t)(n*HW + hw0 + w*64 + t*16 + cc);
      float h0 = acc[s][t][0] + b0, h1 = acc[s][t][1] + b1;
      float h2v = acc[s][t][2] + b2, h3 = acc[s][t][3] + b3;
      if (EPI == 3){
        float4 av4 = *(const float4*)(accin + pb*AST + ch);
        h0 += av4.x; h1 += av4.y; h2v += av4.z; h3 += av4.w;
      }
      if (EPI == 0){
        *(float4*)((float*)outv + pb*OP + ch) = make_float4(h0, h1, h2v, h3);
      } else if (EPI == 1){
        uint2 pk;
        pk.x = (uint_t)f2bf(h0)  | ((uint_t)f2bf(h1)<<16);
        pk.y = (uint_t)f2bf(h2v) | ((uint_t)f2bf(h3)<<16);
        *(uint2*)((ushort_t*)outv + pb*OP + ch) = pk;
      } else {
        ushort_t* op = (ushort_t*)outv + pb*OP;
        uint2 pp, pn;
        pp.x = (uint_t)f2bf(elu1(h0))  | ((uint_t)f2bf(elu1(h1))<<16);
        pp.y = (uint_t)f2bf(elu1(h2v)) | ((uint_t)f2bf(elu1(h3))<<16);
        pn.x = (uint_t)f2bf(elu1(-h0))  | ((uint_t)f2bf(elu1(-h1))<<16);
        pn.y = (uint_t)f2bf(elu1(-h2v)) | ((uint_t)f2bf(elu1(-h3))<<16);
        *(uint2*)(op + ch) = pp;
        *(uint2*)(op + P1o + ch) = pn;
      }
    }
  }
}

// ---------------- attention (faithful masked softmax, fp32 math, bf16 I/O) ----------------
#define RT 8
#define KDIM 16
#define VDIM 80

__global__ __launch_bounds__(256) void k_attn(const ushort_t* __restrict__ Kb,
    const ushort_t* __restrict__ Qb, const ushort_t* __restrict__ Vb, float* __restrict__ out){
  __shared__ float s[RT][HW+1];      // 32.8 KB
  __shared__ float tile[5120];       // phase1: [16][129]; phase3: [64][80]
  __shared__ float q[KDIM][RT];
  const int n  = blockIdx.y;
  const int rb = blockIdx.x*RT;
  const int tid = threadIdx.x;

  if (tid < KDIM*RT){
    int d = tid & 15, r = tid >> 4;
    q[d][r] = bf2f(Qb[(size_t)(n*HW + rb + r)*KDIM + d]);
  }

  // phase 1: s[r][j] = sum_d q[d][r]*K[d][j]   (K pixel-major bf16)
  for (int jt = 0; jt < HW/128; ++jt){
    __syncthreads();
    for (int idx = tid; idx < KDIM*128; idx += 256){
      int d = idx & 15, j = idx >> 4;
      tile[d*129 + j] = bf2f(Kb[(size_t)(n*HW + jt*128 + j)*KDIM + d]);
    }
    __syncthreads();
    #pragma unroll
    for (int k = 0; k < RT*128/256; ++k){
      int item = tid + k*256;
      int r = item >> 7, j = item & 127;
      float a = 0.f;
      #pragma unroll
      for (int d = 0; d < KDIM; ++d) a += q[d][r]*tile[d*129 + j];
      s[r][jt*128 + j] = a;
    }
  }
  __syncthreads();

  // phase 2: faithful torch-tril softmax per row
  {
    int r = tid >> 5, lane = tid & 31;
    int rg = rb + r;
    float m = 0.f;
    for (int j = lane; j < HW; j += 32)
      if (j < rg) m = fmaxf(m, s[r][j]);
    #pragma unroll
    for (int off = 16; off; off >>= 1) m = fmaxf(m, __shfl_xor(m, off, 32));
    float S = 0.f;
    for (int j = lane; j < HW; j += 32)
      if (j < rg) S += expf(s[r][j] - m);
    #pragma unroll
    for (int off = 16; off; off >>= 1) S += __shfl_xor(S, off, 32);
    float Z = S + (float)(HW - rg)*expf(-m);
    float inv = 1.f/(S + 1e-7f*Z);
    for (int j = lane; j < HW; j += 32)
      s[r][j] = (j < rg) ? expf(s[r][j] - m)*inv : 0.f;
  }

  // phase 3: att_v[v][rb+r] = sum_j s[r][j]*V[v][j]  (V pixel-major bf16)
  const int i0 = tid, i1 = tid + 256, i2 = tid + 512;
  const int r_0 = i0/VDIM, v_0 = i0 - r_0*VDIM;
  const int r_1 = i1/VDIM, v_1 = i1 - r_1*VDIM;
  const bool has2 = (i2 < RT*VDIM);
  const int r_2 = has2 ? i2/VDIM : 0;
  const int v_2 = has2 ? (i2 - r_2*VDIM) : 0;
  float acc0 = 0.f, acc1 = 0.f, acc2 = 0.f;

  for (int jt = 0; jt < HW/64; ++jt){
    __syncthreads();
    for (int idx = tid; idx < 64*VDIM; idx += 256){
      int j = idx / VDIM, v = idx - j*VDIM;
      tile[j*VDIM + v] = bf2f(Vb[(size_t)(n*HW + jt*64 + j)*VDIM + v]);
    }
    __syncthreads();
    #pragma unroll 8
    for (int j = 0; j < 64; ++j){
      float w0 = s[r_0][jt*64 + j];
      float w1 = s[r_1][jt*64 + j];
      float w2 = s[r_2][jt*64 + j];
      acc0 += w0*tile[j*VDIM + v_0];
      acc1 += w1*tile[j*VDIM + v_1];
      acc2 += w2*tile[j*VDIM + v_2];
    }
  }
  out[(size_t)(n*HW + rb + r_0)*VDIM + v_0] = acc0;
  out[(size_t)(n*HW + rb + r_1)*VDIM + v_1] = acc1;
  if (has2) out[(size_t)(n*HW + rb + r_2)*VDIM + v_2] = acc2;
}

#define GMM(EPI, Wp, Bp, ACT, ACCIN, OUT, O_, KT, K1_, P1_, CP_, KP_, OP_, P1O_, AST_) \
  { int shm = (32*((KP_)+8) + 16384)*2; \
    k_gmm<EPI><<<dim3(128, ((O_)+31)/32), dim3(256), shm, stream>>>( \
      Wp, Bp, (const ushort_t*)(ACT), ACCIN, OUT, O_, KT, K1_, P1_, CP_, KP_, OP_, P1O_, AST_); }

extern "C" void kernel_launch(void* const* d_in, const int* in_sizes, int n_in,
                              void* d_out, int out_size, void* d_ws, size_t ws_size,
                              hipStream_t stream) {
  const float* x    = (const float*)d_in[0];
  const float* ul   = (const float*)d_in[1];
  const float* bb   = (const float*)d_in[2];
  const float* gkWi = (const float*)d_in[3];  const float* gkbi = (const float*)d_in[4];
  const float* gkWo = (const float*)d_in[5];  const float* gkbo = (const float*)d_in[6];
  const float* gqWi = (const float*)d_in[7];  const float* gqbi = (const float*)d_in[8];
  const float* gqWo = (const float*)d_in[9];  const float* gqbo = (const float*)d_in[10];
  const float* gvWi = (const float*)d_in[11]; const float* gvbi = (const float*)d_in[12];
  const float* gvWo = (const float*)d_in[13]; const float* gvbo = (const float*)d_in[14];
  const float* nkW  = (const float*)d_in[15]; const float* nkb  = (const float*)d_in[16];
  const float* nqW  = (const float*)d_in[17]; const float* nqb  = (const float*)d_in[18];
  const float* nvW  = (const float*)d_in[19]; const float* nvb  = (const float*)d_in[20];
  const float* goWi = (const float*)d_in[21]; const float* gobi = (const float*)d_in[22];
  const float* goWs = (const float*)d_in[23]; const float* gobs = (const float*)d_in[24];
  const float* goWo = (const float*)d_in[25]; const float* gobo = (const float*)d_in[26];
  float* outp = (float*)d_out;
  char* wsb = (char*)d_ws;

  // byte offsets (P = 32768 pixels)
  ushort_t* A  = (ushort_t*)(wsb + 0);          // 352 ch bf16: ce(x_ul_b)  / ce(ul)
  ushort_t* C  = (ushort_t*)(wsb + 23068672);   // 352 ch bf16: ce(h1*)
  ushort_t* D  = (ushort_t*)(wsb + 46137344);   // 340 ch bf16 h2  (also h1o fp32 160)
  ushort_t* E  = (ushort_t*)(wsb + 68419584);   // 336 ch bf16: grn-out / ce(ul_b) / ce(att_v)
  ushort_t* Kp = (ushort_t*)(wsb + 90439680);   // keys bf16 [px][16]
  ushort_t* Qp = (ushort_t*)(wsb + 91488256);   // queries bf16 [px][16]
  ushort_t* Vp = (ushort_t*)(wsb + 92536832);   // values bf16 [px][80]
  float*    AV = (float*)   (wsb + 97779712);   // att_v fp32 [px][80]

  dim3 b256(256);

  // ---- keys path ----
  k_act<0><<<128, b256, 0, stream>>>(x, ul, bb, nullptr, A, 169, 176, 352);
  GMM(2, gkWi, gkbi, A, nullptr, C, 169, 338, 169, 176, 352, 352, 352, 176, 0);
  GMM(1, gkWo, gkbo, C, nullptr, D, 338, 338, 169, 176, 352, 352, 340, 0, 0);
  k_res2<0><<<128, b256, 0, stream>>>(x, ul, bb, D, E, 169, 340, 176, 0);
  GMM(1, nkW, nkb, E, nullptr, Kp, 16, 169, 169, 176, 176, 192, 16, 0, 0);

  // ---- queries path ----
  k_act<1><<<128, b256, 0, stream>>>(x, ul, bb, nullptr, E, 166, 168, 336);
  GMM(2, gqWi, gqbi, E, nullptr, C, 166, 332, 166, 168, 336, 352, 336, 168, 0);
  GMM(1, gqWo, gqbo, C, nullptr, D, 332, 332, 166, 168, 336, 352, 332, 0, 0);
  k_res2<0><<<128, b256, 0, stream>>>(x, ul, bb, D, E, 166, 332, 168, 1);
  GMM(1, nqW, nqb, E, nullptr, Qp, 16, 166, 166, 168, 168, 192, 16, 0, 0);

  // ---- values path ----
  GMM(2, gvWi, gvbi, A, nullptr, C, 169, 338, 169, 176, 352, 352, 352, 176, 0);
  GMM(1, gvWo, gvbo, C, nullptr, D, 338, 338, 169, 176, 352, 352, 340, 0, 0);
  k_res2<0><<<128, b256, 0, stream>>>(x, ul, bb, D, E, 169, 340, 176, 0);
  GMM(1, nvW, nvb, E, nullptr, Vp, 80, 169, 169, 176, 176, 192, 80, 0, 0);

  // ---- attention ----
  k_attn<<<dim3(HW/RT, NBATCH), b256, 0, stream>>>(Kp, Qp, Vp, AV);

  // ---- output grn ----
  k_act<2><<<128, b256, 0, stream>>>(x, ul, bb, nullptr, A, 160, 160, 320);
  k_act<3><<<128, b256, 0, stream>>>(x, ul, bb, AV, E, 80, 80, 160);
  GMM(0, goWi, gobi, A, nullptr, (float*)D, 160, 320, 320, 320, 320, 320, 160, 0, 0);
  GMM(3, goWs, gobs, E, (const float*)D, C, 160, 160, 160, 160, 160, 160, 320, 160, 160);
  GMM(1, goWo, gobo, C, nullptr, D, 320, 320, 320, 320, 320, 320, 320, 0, 0);
  k_res2<1><<<128, b256, 0, stream>>>(x, ul, bb, D, outp, 160, 320, 160, 2);
}

// Round 3
// 1063.136 us; speedup vs baseline: 5.1151x; 2.0286x over previous
//
#include <hip/hip_runtime.h>
#include <cstddef>
#include <cstdint>

#define HW 1024
#define NBATCH 32

typedef unsigned short ushort_t;
typedef unsigned int uint_t;
typedef short s16x8 __attribute__((ext_vector_type(8)));
typedef float f32x4 __attribute__((ext_vector_type(4)));
typedef float f32x16 __attribute__((ext_vector_type(16)));
typedef unsigned int u32x4 __attribute__((ext_vector_type(4)));

__device__ __forceinline__ float elu1(float z){ return z > 0.f ? z : expm1f(z); }
__device__ __forceinline__ float sigm(float z){ return 1.f/(1.f+expf(-z)); }
__device__ __forceinline__ ushort_t f2bf(float f){
  uint_t u = __builtin_bit_cast(uint_t, f);
  u += 0x7FFFu + ((u >> 16) & 1u);
  return (ushort_t)(u >> 16);
}
__device__ __forceinline__ float bf2f(ushort_t h){
  uint_t u = ((uint_t)h) << 16;
  return __builtin_bit_cast(float, u);
}
__device__ __forceinline__ uint_t cvtpk(float lo, float hi){
  uint_t r;
  asm("v_cvt_pk_bf16_f32 %0, %1, %2" : "=v"(r) : "v"(lo), "v"(hi));
  return r;
}
__device__ __forceinline__ void gload_lds16(const void* g, void* l){
  __builtin_amdgcn_global_load_lds((const __attribute__((address_space(1))) unsigned int*)g,
                                   (__attribute__((address_space(3))) unsigned int*)l, 16, 0, 0);
}

// gm: 0 = concat(x[3],ul[160],b[6]) (169 ch), 1 = concat(ul,b) (166), 2 = ul (160)
__device__ __forceinline__ const float* src_ptr(const float* x, const float* ul, const float* b,
                                                int n, int c, int gm){
  if (gm == 0){
    if (c < 3)   return x  + ((size_t)n*3   + c)*HW;
    if (c < 163) return ul + ((size_t)n*160 + (c-3))*HW;
    return b + ((size_t)n*6 + (c-163))*HW;
  } else if (gm == 1){
    if (c < 160) return ul + ((size_t)n*160 + c)*HW;
    return b + ((size_t)n*6 + (c-160))*HW;
  }
  return ul + ((size_t)n*160 + c)*HW;
}

// ---------------- concat_elu -> bf16 pixel-major act buffer ----------------
template<int GM>
__global__ void k_act(const float* __restrict__ x, const float* __restrict__ ul,
                      const float* __restrict__ b, const float* __restrict__ av,
                      ushort_t* __restrict__ out, int Cb, int P1, int CP){
  int pxg = blockIdx.x*256 + threadIdx.x;
  int n = pxg >> 10, hw = pxg & 1023;
  ushort_t* orow = out + (size_t)pxg * CP;
  for (int c8 = 0; c8 < P1; c8 += 8){
    ushort_t pbuf[8], nbuf[8];
    #pragma unroll
    for (int j = 0; j < 8; ++j){
      int c = c8 + j;
      float s = 0.f;
      if (c < Cb){
        if (GM == 3) s = av[((size_t)(n*80 + c))*HW + hw];
        else         s = src_ptr(x, ul, b, n, c, GM)[hw];
      }
      pbuf[j] = f2bf(elu1(s));
      nbuf[j] = f2bf(elu1(-s));
    }
    uint4 up, un;
    up.x = (uint_t)pbuf[0] | ((uint_t)pbuf[1]<<16);
    up.y = (uint_t)pbuf[2] | ((uint_t)pbuf[3]<<16);
    up.z = (uint_t)pbuf[4] | ((uint_t)pbuf[5]<<16);
    up.w = (uint_t)pbuf[6] | ((uint_t)pbuf[7]<<16);
    un.x = (uint_t)nbuf[0] | ((uint_t)nbuf[1]<<16);
    un.y = (uint_t)nbuf[2] | ((uint_t)nbuf[3]<<16);
    un.z = (uint_t)nbuf[4] | ((uint_t)nbuf[5]<<16);
    un.w = (uint_t)nbuf[6] | ((uint_t)nbuf[7]<<16);
    *(uint4*)(orow + c8)      = up;
    *(uint4*)(orow + P1 + c8) = un;
  }
}

// ---------------- grn residual ----------------
template<int FINAL>
__global__ void k_res2(const float* __restrict__ x, const float* __restrict__ ul,
                       const float* __restrict__ b, const ushort_t* __restrict__ h2,
                       void* __restrict__ outv, int C, int OPh, int P1g, int gm){
  int pxg = blockIdx.x*256 + threadIdx.x;
  int n = pxg >> 10, hw = pxg & 1023;
  const ushort_t* hrow = h2 + (size_t)pxg*OPh;
  const int lim = FINAL ? C : P1g;
  for (int c8 = 0; c8 < lim; c8 += 8){
    ushort_t buf[8];
    #pragma unroll
    for (int j = 0; j < 8; ++j){
      int c = c8 + j;
      float r = 0.f;
      if (c < C){
        float ga = bf2f(hrow[c]);
        float gb = bf2f(hrow[C + c]);
        float s  = src_ptr(x, ul, b, n, c, gm)[hw];
        r = s + ga*sigm(gb);
      }
      if (FINAL){ if (c < C) ((float*)outv)[((size_t)n*C + c)*HW + hw] = r; }
      else buf[j] = f2bf(r);
    }
    if (!FINAL){
      uint4 u;
      u.x = (uint_t)buf[0] | ((uint_t)buf[1]<<16);
      u.y = (uint_t)buf[2] | ((uint_t)buf[3]<<16);
      u.z = (uint_t)buf[4] | ((uint_t)buf[5]<<16);
      u.w = (uint_t)buf[6] | ((uint_t)buf[7]<<16);
      *(uint4*)((ushort_t*)outv + (size_t)pxg*P1g + c8) = u;
    }
  }
}

// ---------------- weight pre-convert: fp32 [O][Kt] -> padded bf16 [Opad][Kpad] ----------------
struct SPtrs { const float* p[12]; };
struct WCfg  { int dst[12], O[12], Kt[12], K1[12], P1[12], Opad[12], Kpad[12]; };

__global__ void k_wconv(SPtrs sp, WCfg c, ushort_t* __restrict__ Wb){
  int d = blockIdx.y;
  const float* src = sp.p[d];
  int O = c.O[d], Kt = c.Kt[d], K1 = c.K1[d], P1 = c.P1[d], Op = c.Opad[d], Kp = c.Kpad[d];
  ushort_t* dst = Wb + c.dst[d];
  int total = Op*Kp, K2 = Kt - K1;
  for (int i = blockIdx.x*256 + threadIdx.x; i < total; i += 32*256){
    int o = i / Kp, kk = i - o*Kp;
    int k = (kk < K1) ? kk : ((kk >= P1 && kk < P1 + K2) ? (K1 + kk - P1) : -1);
    float v = (o < O && k >= 0) ? src[(size_t)o*Kt + k] : 0.f;
    dst[i] = f2bf(v);
  }
}

// ---------------- MFMA GEMM: 256px x 64o tile, A from L2->regs, B wave-private LDS ----------------
// EPI: 0 fp32 pixel-major(OP); 1 bf16 pixel-major(OP); 2 ce bf16 (neg at P1o, stride OP);
//      3 = EPI2 + accin fp32 (stride AST); 4 bf16 channel-major (ch-rows, OP = per-n ch count)
template<int EPI>
__global__ __launch_bounds__(256) void k_gmm2(const ushort_t* __restrict__ Wb, const float* __restrict__ bias,
    const ushort_t* __restrict__ act, const float* __restrict__ accin, void* __restrict__ outv,
    int O, int Kpad, int CP, int OP, int P1o, int AST)
{
  __shared__ ushort_t Blds[4][2][2048];   // per-wave 2x4KB dbuf
  const int tid = threadIdx.x;
  const int w = tid >> 6, l = tid & 63;
  const int n = blockIdx.x >> 2, hw0 = (blockIdx.x & 3)*256;
  const int o0 = blockIdx.y*64;

  const ushort_t* actw = act + (size_t)(n*HW + hw0 + w*64)*CP;
  const ushort_t* Wbo  = Wb + (size_t)o0*Kpad;

#define STAGE2(bufi, ktv) do { \
    int cl_ = (l & 3) ^ ((l >> 4) & 2); \
    _Pragma("unroll") \
    for (int s_ = 0; s_ < 4; ++s_){ \
      const ushort_t* g_ = actw + (size_t)(s_*16 + (l>>2))*CP + (ktv)*32 + cl_*8; \
      gload_lds16(g_, &Blds[w][bufi][s_*512]); \
    } \
  } while(0)

  f32x4 acc[4][4];
  #pragma unroll
  for (int i = 0; i < 4; ++i)
    #pragma unroll
    for (int j = 0; j < 4; ++j) acc[i][j] = (f32x4){0.f,0.f,0.f,0.f};

  const int NT = Kpad >> 5;
  STAGE2(0, 0);
  for (int kt = 0; kt < NT; ++kt){
    int cur = kt & 1;
    const ushort_t* Ab = Wbo + (size_t)(l&15)*Kpad + kt*32 + (l>>4)*8;
    s16x8 a0 = *(const s16x8*)(Ab);
    s16x8 a1 = *(const s16x8*)(Ab + 16*Kpad);
    s16x8 a2 = *(const s16x8*)(Ab + 32*Kpad);
    s16x8 a3 = *(const s16x8*)(Ab + 48*Kpad);
    if (kt + 1 < NT) STAGE2(cur^1, kt+1);
    asm volatile("s_waitcnt vmcnt(4)" ::: "memory");
    const ushort_t* Bb = &Blds[w][cur][0];
    const int chp = ((l>>4) ^ ((l>>2)&2))*8;
    #pragma unroll
    for (int po = 0; po < 4; ++po){
      s16x8 bv = *(const s16x8*)(Bb + po*512 + (l&15)*32 + chp);
      acc[po][0] = __builtin_amdgcn_mfma_f32_16x16x32_bf16(a0, bv, acc[po][0], 0, 0, 0);
      acc[po][1] = __builtin_amdgcn_mfma_f32_16x16x32_bf16(a1, bv, acc[po][1], 0, 0, 0);
      acc[po][2] = __builtin_amdgcn_mfma_f32_16x16x32_bf16(a2, bv, acc[po][2], 0, 0, 0);
      acc[po][3] = __builtin_amdgcn_mfma_f32_16x16x32_bf16(a3, bv, acc[po][3], 0, 0, 0);
    }
  }
#undef STAGE2

  // epilogue: D frag col = l&15 (px), row = (l>>4)*4 + reg (o)
  const int g = l >> 4, cc = l & 15;
  #pragma unroll
  for (int oo = 0; oo < 4; ++oo){
    int ch = o0 + oo*16 + g*4;
    if (ch >= O) continue;
    float b0 = bias[ch];
    float b1 = (ch+1 < O) ? bias[ch+1] : 0.f;
    float b2 = (ch+2 < O) ? bias[ch+2] : 0.f;
    float b3 = (ch+3 < O) ? bias[ch+3] : 0.f;
    #pragma unroll
    for (int po = 0; po < 4; ++po){
      int px = hw0 + w*64 + po*16 + cc;
      size_t pb = (size_t)n*HW + px;
      f32x4 a = acc[po][oo];
      float h0 = a[0]+b0, h1 = a[1]+b1, h2v = a[2]+b2, h3 = a[3]+b3;
      if (EPI == 3){
        float4 av4 = *(const float4*)(accin + pb*AST + ch);
        h0 += av4.x; h1 += av4.y; h2v += av4.z; h3 += av4.w;
      }
      if (EPI == 0){
        *(float4*)((float*)outv + pb*OP + ch) = make_float4(h0, h1, h2v, h3);
      } else if (EPI == 1){
        uint2 pk;
        pk.x = (uint_t)f2bf(h0)  | ((uint_t)f2bf(h1)<<16);
        pk.y = (uint_t)f2bf(h2v) | ((uint_t)f2bf(h3)<<16);
        *(uint2*)((ushort_t*)outv + pb*OP + ch) = pk;
      } else if (EPI == 2 || EPI == 3){
        ushort_t* op = (ushort_t*)outv + pb*OP;
        uint2 pp, pn;
        pp.x = (uint_t)f2bf(elu1(h0))  | ((uint_t)f2bf(elu1(h1))<<16);
        pp.y = (uint_t)f2bf(elu1(h2v)) | ((uint_t)f2bf(elu1(h3))<<16);
        pn.x = (uint_t)f2bf(elu1(-h0))  | ((uint_t)f2bf(elu1(-h1))<<16);
        pn.y = (uint_t)f2bf(elu1(-h2v)) | ((uint_t)f2bf(elu1(-h3))<<16);
        *(uint2*)(op + ch) = pp;
        *(uint2*)(op + P1o + ch) = pn;
      } else {
        ushort_t* ob = (ushort_t*)outv;
        float hv[4] = {h0, h1, h2v, h3};
        #pragma unroll
        for (int i = 0; i < 4; ++i)
          if (ch + i < O) ob[((size_t)n*OP + ch + i)*HW + px] = f2bf(hv[i]);
      }
    }
  }
}

// ---------------- MFMA flash attention, faithful torch-tril softmax ----------------
__global__ __launch_bounds__(64) void k_attn2(const ushort_t* __restrict__ Kp,
    const ushort_t* __restrict__ Qp, const ushort_t* __restrict__ Vc, float* __restrict__ AV){
  const int l = threadIdx.x;
  const int qt = blockIdx.x, n = blockIdx.y;
  const int hi = l >> 5, qcol = l & 31;
  const int qg = qt*32 + qcol;

  s16x8 bq = *(const s16x8*)(Qp + ((size_t)(n*HW + qg))*16 + hi*8);

  f32x16 acc0, acc1, acc2;
  #pragma unroll
  for (int r = 0; r < 16; ++r){ acc0[r]=0.f; acc1[r]=0.f; acc2[r]=0.f; }
  float m = 0.f, S = 0.f;
  const int nkt = qt + 1;

  for (int kt = 0; kt < nkt; ++kt){
    const int j0 = kt*32;
    s16x8 ak = *(const s16x8*)(Kp + ((size_t)(n*HW + j0 + qcol))*16 + hi*8);
    f32x16 zc;
    #pragma unroll
    for (int r = 0; r < 16; ++r) zc[r] = 0.f;
    f32x16 p = __builtin_amdgcn_mfma_f32_32x32x16_bf16(ak, bq, zc, 0, 0, 0);

    float ps[16];
    float tmax = -3.0e38f;
    const bool diag = (kt == qt);
    #pragma unroll
    for (int r = 0; r < 16; ++r){
      int kk = j0 + (r&3) + 8*(r>>2) + 4*hi;
      float sv = p[r];
      if (diag && kk >= qg) sv = -3.0e38f;
      ps[r] = sv;
      tmax = fmaxf(tmax, sv);
    }
    tmax = fmaxf(tmax, __shfl_xor(tmax, 32));
    if (tmax > m + 8.f){
      float f = __expf(m - tmax);
      S *= f;
      #pragma unroll
      for (int r = 0; r < 16; ++r){ acc0[r]*=f; acc1[r]*=f; acc2[r]*=f; }
      m = tmax;
    }
    float pe[16], ts = 0.f;
    #pragma unroll
    for (int r = 0; r < 16; ++r){ pe[r] = __expf(ps[r] - m); ts += pe[r]; }
    S += ts + __shfl_xor(ts, 32);

    uint_t w0 = cvtpk(pe[0],  pe[1]),  w1 = cvtpk(pe[2],  pe[3]);
    uint_t w2 = cvtpk(pe[4],  pe[5]),  w3 = cvtpk(pe[6],  pe[7]);
    uint_t w4 = cvtpk(pe[8],  pe[9]),  w5 = cvtpk(pe[10], pe[11]);
    uint_t w6 = cvtpk(pe[12], pe[13]), w7 = cvtpk(pe[14], pe[15]);
    uint_t o0 = __shfl_xor((int)w0, 32), o1 = __shfl_xor((int)w1, 32);
    uint_t o2 = __shfl_xor((int)w2, 32), o3 = __shfl_xor((int)w3, 32);
    uint_t o4 = __shfl_xor((int)w4, 32), o5 = __shfl_xor((int)w5, 32);
    uint_t o6 = __shfl_xor((int)w6, 32), o7 = __shfl_xor((int)w7, 32);
    u32x4 f0, f1;
    f0.x = hi ? o2 : w0; f0.y = hi ? o3 : w1; f0.z = hi ? w2 : o0; f0.w = hi ? w3 : o1;
    f1.x = hi ? o6 : w4; f1.y = hi ? o7 : w5; f1.z = hi ? w6 : o4; f1.w = hi ? w7 : o5;
    s16x8 pb0 = __builtin_bit_cast(s16x8, f0);
    s16x8 pb1 = __builtin_bit_cast(s16x8, f1);

    const ushort_t* vb = Vc + ((size_t)(n*96 + qcol))*HW + j0 + hi*8;
    s16x8 v00 = *(const s16x8*)(vb);
    s16x8 v01 = *(const s16x8*)(vb + 16);
    s16x8 v10 = *(const s16x8*)(vb + 32*HW);
    s16x8 v11 = *(const s16x8*)(vb + 32*HW + 16);
    s16x8 v20 = *(const s16x8*)(vb + 64*HW);
    s16x8 v21 = *(const s16x8*)(vb + 64*HW + 16);
    acc0 = __builtin_amdgcn_mfma_f32_32x32x16_bf16(v00, pb0, acc0, 0, 0, 0);
    acc0 = __builtin_amdgcn_mfma_f32_32x32x16_bf16(v01, pb1, acc0, 0, 0, 0);
    acc1 = __builtin_amdgcn_mfma_f32_32x32x16_bf16(v10, pb0, acc1, 0, 0, 0);
    acc1 = __builtin_amdgcn_mfma_f32_32x32x16_bf16(v11, pb1, acc1, 0, 0, 0);
    acc2 = __builtin_amdgcn_mfma_f32_32x32x16_bf16(v20, pb0, acc2, 0, 0, 0);
    acc2 = __builtin_amdgcn_mfma_f32_32x32x16_bf16(v21, pb1, acc2, 0, 0, 0);
  }

  float Z = S + (float)(HW - qg)*__expf(-m);
  float inv = 1.f/(S + 1e-7f*Z);
  #pragma unroll
  for (int r = 0; r < 16; ++r){
    int vr = (r&3) + 8*(r>>2) + 4*hi;
    AV[((size_t)(n*80 + vr))*HW + qg]      = acc0[r]*inv;
    AV[((size_t)(n*80 + 32 + vr))*HW + qg] = acc1[r]*inv;
    if (64 + vr < 80) AV[((size_t)(n*80 + 64 + vr))*HW + qg] = acc2[r]*inv;
  }
}

extern "C" void kernel_launch(void* const* d_in, const int* in_sizes, int n_in,
                              void* d_out, int out_size, void* d_ws, size_t ws_size,
                              hipStream_t stream) {
  const float* x    = (const float*)d_in[0];
  const float* ul   = (const float*)d_in[1];
  const float* bb   = (const float*)d_in[2];
  const float* gkWi = (const float*)d_in[3];  const float* gkbi = (const float*)d_in[4];
  const float* gkWo = (const float*)d_in[5];  const float* gkbo = (const float*)d_in[6];
  const float* gqWi = (const float*)d_in[7];  const float* gqbi = (const float*)d_in[8];
  const float* gqWo = (const float*)d_in[9];  const float* gqbo = (const float*)d_in[10];
  const float* gvWi = (const float*)d_in[11]; const float* gvbi = (const float*)d_in[12];
  const float* gvWo = (const float*)d_in[13]; const float* gvbo = (const float*)d_in[14];
  const float* nkW  = (const float*)d_in[15]; const float* nkb  = (const float*)d_in[16];
  const float* nqW  = (const float*)d_in[17]; const float* nqb  = (const float*)d_in[18];
  const float* nvW  = (const float*)d_in[19]; const float* nvb  = (const float*)d_in[20];
  const float* goWi = (const float*)d_in[21]; const float* gobi = (const float*)d_in[22];
  const float* goWs = (const float*)d_in[23]; const float* gobs = (const float*)d_in[24];
  const float* goWo = (const float*)d_in[25]; const float* gobo = (const float*)d_in[26];
  float* outp = (float*)d_out;
  char* wsb = (char*)d_ws;

  ushort_t* R0 = (ushort_t*)(wsb + 0);           // 23.07MB: ce_xulb / ce_ulb / h1o(fp32)
  ushort_t* R1 = (ushort_t*)(wsb + 23068672);    // 23.07MB: ce_h1 / ce_ul / ce_h1o
  ushort_t* R2 = (ushort_t*)(wsb + 46137344);    // 25.17MB: h2
  ushort_t* R3 = (ushort_t*)(wsb + 71303168);    // 12.58MB: grn-out / ce_attv
  ushort_t* Kp = (ushort_t*)(wsb + 83886080);    // [32][1024][16] bf16
  ushort_t* Qp = (ushort_t*)(wsb + 84934656);
  ushort_t* Vc = (ushort_t*)(wsb + 85983232);    // [32][96][1024] bf16 chan-major
  float*    AV = (float*)   (wsb + 92274688);    // [32][80][1024] fp32 chan-major
  ushort_t* Wb = (ushort_t*)(wsb + 102760448);   // 1.74MB bf16 weights

  // weight descs: gkWi gkWo nkW gqWi gqWo nqW gvWi gvWo nvW goWi goWs goWo
  static const int dDst[12]  = {0,67584,202752,215040,282624,417792,430080,497664,632832,657408,718848,749568};
  static const int dO[12]    = {169,338,16,166,332,16,169,338,80,160,160,320};
  static const int dKt[12]   = {338,338,169,332,332,166,338,338,169,320,160,320};
  static const int dK1[12]   = {169,169,169,166,166,166,169,169,169,160,80,320};
  static const int dP1[12]   = {176,176,9999,176,176,9999,176,176,9999,160,80,9999};
  static const int dOp[12]   = {192,384,64,192,384,64,192,384,128,192,192,384};
  static const int dKp[12]   = {352,352,192,352,352,192,352,352,192,320,160,320};

  SPtrs sp; WCfg wc;
  const float* srcs[12] = {gkWi,gkWo,nkW,gqWi,gqWo,nqW,gvWi,gvWo,nvW,goWi,goWs,goWo};
  for (int i = 0; i < 12; ++i){
    sp.p[i] = srcs[i];
    wc.dst[i]=dDst[i]; wc.O[i]=dO[i]; wc.Kt[i]=dKt[i]; wc.K1[i]=dK1[i];
    wc.P1[i]=dP1[i]; wc.Opad[i]=dOp[i]; wc.Kpad[i]=dKp[i];
  }

  dim3 b256(256), b64t(64);
  k_wconv<<<dim3(32,12), b256, 0, stream>>>(sp, wc, Wb);

#define GMM2(EPI, DI, BIASP, ACT, ACCIN, OUT, O_, CP_, OP_, P1O_, AST_) \
  k_gmm2<EPI><<<dim3(128, dOp[DI]/64), b256, 0, stream>>>( \
    Wb + dDst[DI], BIASP, (const ushort_t*)(ACT), ACCIN, OUT, O_, dKp[DI], CP_, OP_, P1O_, AST_)

  // ---- keys path ----
  k_act<0><<<128, b256, 0, stream>>>(x, ul, bb, nullptr, R0, 169, 176, 352);
  GMM2(2, 0, gkbi, R0, nullptr, R1, 169, 352, 352, 176, 0);
  GMM2(1, 1, gkbo, R1, nullptr, R2, 338, 352, 384, 0, 0);
  k_res2<0><<<128, b256, 0, stream>>>(x, ul, bb, R2, R3, 169, 384, 192, 0);
  GMM2(1, 2, nkb, R3, nullptr, Kp, 16, 192, 16, 0, 0);

  // ---- values path ----
  GMM2(2, 6, gvbi, R0, nullptr, R1, 169, 352, 352, 176, 0);
  GMM2(1, 7, gvbo, R1, nullptr, R2, 338, 352, 384, 0, 0);
  k_res2<0><<<128, b256, 0, stream>>>(x, ul, bb, R2, R3, 169, 384, 192, 0);
  GMM2(4, 8, nvb, R3, nullptr, Vc, 80, 192, 96, 0, 0);

  // ---- queries path ----
  k_act<1><<<128, b256, 0, stream>>>(x, ul, bb, nullptr, R0, 166, 176, 352);
  GMM2(2, 3, gqbi, R0, nullptr, R1, 166, 352, 352, 176, 0);
  GMM2(1, 4, gqbo, R1, nullptr, R2, 332, 352, 384, 0, 0);
  k_res2<0><<<128, b256, 0, stream>>>(x, ul, bb, R2, R3, 166, 384, 192, 1);
  GMM2(1, 5, nqb, R3, nullptr, Qp, 16, 192, 16, 0, 0);

  // ---- attention ----
  k_attn2<<<dim3(32, 32), b64t, 0, stream>>>(Kp, Qp, Vc, AV);

  // ---- output grn ----
  k_act<2><<<128, b256, 0, stream>>>(x, ul, bb, nullptr, R1, 160, 160, 320);
  k_act<3><<<128, b256, 0, stream>>>(x, ul, bb, AV, R3, 80, 80, 160);
  GMM2(0, 9, gobi, R1, nullptr, (float*)R0, 160, 320, 160, 0, 0);
  GMM2(3, 10, gobs, R3, (const float*)R0, R1, 160, 160, 320, 160, 160);
  GMM2(1, 11, gobo, R1, nullptr, R2, 320, 320, 320, 0, 0);
  k_res2<1><<<128, b256, 0, stream>>>(x, ul, bb, R2, outp, 160, 320, 0, 2);
}

// Round 5
// 474.029 us; speedup vs baseline: 11.4719x; 2.2428x over previous
//
#include <hip/hip_runtime.h>
#include <cstddef>
#include <cstdint>

#define HW 1024
#define NBATCH 32

typedef unsigned short ushort_t;
typedef unsigned int uint_t;
typedef short s16x8 __attribute__((ext_vector_type(8)));
typedef float f32x4 __attribute__((ext_vector_type(4)));
typedef float f32x16 __attribute__((ext_vector_type(16)));
typedef unsigned int u32x4 __attribute__((ext_vector_type(4)));

__device__ __forceinline__ float elu1(float z){ return z > 0.f ? z : __expf(z) - 1.f; }
__device__ __forceinline__ float sigm(float z){ return 1.f/(1.f+__expf(-z)); }
__device__ __forceinline__ ushort_t f2bf(float f){
  uint_t u = __builtin_bit_cast(uint_t, f);
  u += 0x7FFFu + ((u >> 16) & 1u);
  return (ushort_t)(u >> 16);
}
__device__ __forceinline__ float bf2f(ushort_t h){
  uint_t u = ((uint_t)h) << 16;
  return __builtin_bit_cast(float, u);
}
__device__ __forceinline__ uint_t cvtpk(float lo, float hi){
  uint_t r;
  asm("v_cvt_pk_bf16_f32 %0, %1, %2" : "=v"(r) : "v"(lo), "v"(hi));
  return r;
}
__device__ __forceinline__ void gload_lds16(const void* g, void* l){
  __builtin_amdgcn_global_load_lds((const __attribute__((address_space(1))) unsigned int*)g,
                                   (__attribute__((address_space(3))) unsigned int*)l, 16, 0, 0);
}

// gm: 0 = concat(x[3],ul[160],b[6]) (169 ch), 1 = concat(ul,b) (166), 2 = ul (160)
__device__ __forceinline__ const float* src_ptr(const float* x, const float* ul, const float* b,
                                                int n, int c, int gm){
  if (gm == 0){
    if (c < 3)   return x  + ((size_t)n*3   + c)*HW;
    if (c < 163) return ul + ((size_t)n*160 + (c-3))*HW;
    return b + ((size_t)n*6 + (c-163))*HW;
  } else if (gm == 1){
    if (c < 160) return ul + ((size_t)n*160 + c)*HW;
    return b + ((size_t)n*6 + (c-160))*HW;
  }
  return ul + ((size_t)n*160 + c)*HW;
}

// ---------------- concat_elu -> bf16 pixel-major; grid (pxblocks, P1/8) ----------------
template<int GM>
__global__ void k_act(const float* __restrict__ x, const float* __restrict__ ul,
                      const float* __restrict__ b, const float* __restrict__ av,
                      ushort_t* __restrict__ out, int Cb, int P1, int CP){
  int pxg = blockIdx.x*256 + threadIdx.x;
  int n = pxg >> 10, hw = pxg & 1023;
  int c8 = blockIdx.y*8;
  ushort_t* orow = out + (size_t)pxg * CP;
  ushort_t pbuf[8], nbuf[8];
  #pragma unroll
  for (int j = 0; j < 8; ++j){
    int c = c8 + j;
    float s = 0.f;
    if (c < Cb){
      if (GM == 3) s = av[((size_t)(n*80 + c))*HW + hw];
      else         s = src_ptr(x, ul, b, n, c, GM)[hw];
    }
    pbuf[j] = f2bf(elu1(s));
    nbuf[j] = f2bf(elu1(-s));
  }
  uint4 up, un;
  up.x = (uint_t)pbuf[0] | ((uint_t)pbuf[1]<<16);
  up.y = (uint_t)pbuf[2] | ((uint_t)pbuf[3]<<16);
  up.z = (uint_t)pbuf[4] | ((uint_t)pbuf[5]<<16);
  up.w = (uint_t)pbuf[6] | ((uint_t)pbuf[7]<<16);
  un.x = (uint_t)nbuf[0] | ((uint_t)nbuf[1]<<16);
  un.y = (uint_t)nbuf[2] | ((uint_t)nbuf[3]<<16);
  un.z = (uint_t)nbuf[4] | ((uint_t)nbuf[5]<<16);
  un.w = (uint_t)nbuf[6] | ((uint_t)nbuf[7]<<16);
  *(uint4*)(orow + c8)      = up;
  *(uint4*)(orow + P1 + c8) = un;
}

// ---------------- weight pre-convert ----------------
// fp32 [O][Kt] -> padded bf16 [Opad][Kpad]; col map kk<K1->kk, [P1,P1+K2)->K1+kk-P1, else 0.
// If Oh>0 (fused-res2 Wo layout): dst row o<192 -> src row o (valid o<Oh); o>=192 -> src Oh+(o-192).
struct SPtrs { const float* p[12]; };
struct WCfg  { int dst[12], O[12], Kt[12], K1[12], P1[12], Opad[12], Kpad[12], Oh[12]; };

__global__ void k_wconv(SPtrs sp, WCfg c, ushort_t* __restrict__ Wb){
  int d = blockIdx.y;
  const float* src = sp.p[d];
  int O = c.O[d], Kt = c.Kt[d], K1 = c.K1[d], P1 = c.P1[d], Op = c.Opad[d], Kp = c.Kpad[d], Oh = c.Oh[d];
  ushort_t* dst = Wb + c.dst[d];
  int total = Op*Kp, K2 = Kt - K1;
  for (int i = blockIdx.x*256 + threadIdx.x; i < total; i += 32*256){
    int o = i / Kp, kk = i - o*Kp;
    int k = (kk < K1) ? kk : ((kk >= P1 && kk < P1 + K2) ? (K1 + kk - P1) : -1);
    int so; bool rv;
    if (Oh > 0){
      if (o < 192){ so = o; rv = (o < Oh); }
      else        { so = Oh + (o - 192); rv = ((o - 192) < Oh); }
    } else { so = o; rv = (o < O); }
    float v = (rv && k >= 0) ? src[(size_t)so*Kt + k] : 0.f;
    dst[i] = f2bf(v);
  }
}

// ---------------- MFMA GEMM: 256px x 64o tile, A from L2->regs, B wave-private LDS ----------------
// EPI: 0 fp32 pixel-major(OP); 1 bf16 pixel-major(OP); 2 ce bf16 (neg at P1o, stride OP);
//      3 = EPI2 + accin fp32 (stride AST); 4 bf16 channel-major (OP = per-n ch rows);
//      5 fused grn-residual -> bf16 pixel-major(OP)  [O=Creal, P1o=gm, paired Wo layout]
//      6 fused grn-residual -> fp32 channel-major out [O=Creal, P1o=gm]
template<int EPI>
__global__ __launch_bounds__(256) void k_gmm2(const ushort_t* __restrict__ Wb, const float* __restrict__ bias,
    const ushort_t* __restrict__ act, const float* __restrict__ accin, void* __restrict__ outv,
    const float* __restrict__ xp, const float* __restrict__ ulp, const float* __restrict__ bp,
    int O, int Kpad, int CP, int OP, int P1o, int AST)
{
  __shared__ ushort_t Blds[4][2][2048];   // per-wave 2x4KB dbuf
  const int tid = threadIdx.x;
  const int w = tid >> 6, l = tid & 63;
  const int n = blockIdx.x >> 2, hw0 = (blockIdx.x & 3)*256;
  const bool FUSED = (EPI >= 5);
  const int o0 = blockIdx.y*(FUSED ? 32 : 64);

  const ushort_t* actw = act + (size_t)(n*HW + hw0 + w*64)*CP;
  const ushort_t* Wbo  = Wb + (size_t)o0*Kpad;
  const size_t r2off = FUSED ? (size_t)192*Kpad : (size_t)32*Kpad;

#define STAGE2(bufi, ktv) do { \
    int cl_ = (l & 3) ^ ((l >> 4) & 2); \
    _Pragma("unroll") \
    for (int s_ = 0; s_ < 4; ++s_){ \
      const ushort_t* g_ = actw + (size_t)(s_*16 + (l>>2))*CP + (ktv)*32 + cl_*8; \
      gload_lds16(g_, &Blds[w][bufi][s_*512]); \
    } \
  } while(0)

  f32x4 acc[4][4];
  #pragma unroll
  for (int i = 0; i < 4; ++i)
    #pragma unroll
    for (int j = 0; j < 4; ++j) acc[i][j] = (f32x4){0.f,0.f,0.f,0.f};

  const int NT = Kpad >> 5;
  STAGE2(0, 0);
  for (int kt = 0; kt < NT; ++kt){
    int cur = kt & 1;
    const ushort_t* Ab = Wbo + (size_t)(l&15)*Kpad + kt*32 + (l>>4)*8;
    s16x8 a0 = *(const s16x8*)(Ab);
    s16x8 a1 = *(const s16x8*)(Ab + 16*Kpad);
    s16x8 a2 = *(const s16x8*)(Ab + r2off);
    s16x8 a3 = *(const s16x8*)(Ab + r2off + 16*Kpad);
    if (kt + 1 < NT) STAGE2(cur^1, kt+1);
    asm volatile("s_waitcnt vmcnt(4)" ::: "memory");
    const ushort_t* Bb = &Blds[w][cur][0];
    const int chp = ((l>>4) ^ ((l>>2)&2))*8;
    #pragma unroll
    for (int po = 0; po < 4; ++po){
      s16x8 bv = *(const s16x8*)(Bb + po*512 + (l&15)*32 + chp);
      acc[po][0] = __builtin_amdgcn_mfma_f32_16x16x32_bf16(a0, bv, acc[po][0], 0, 0, 0);
      acc[po][1] = __builtin_amdgcn_mfma_f32_16x16x32_bf16(a1, bv, acc[po][1], 0, 0, 0);
      acc[po][2] = __builtin_amdgcn_mfma_f32_16x16x32_bf16(a2, bv, acc[po][2], 0, 0, 0);
      acc[po][3] = __builtin_amdgcn_mfma_f32_16x16x32_bf16(a3, bv, acc[po][3], 0, 0, 0);
    }
  }
#undef STAGE2

  // D frag: col = l&15 (px), row = (l>>4)*4 + reg
  const int g = l >> 4, cc = l & 15;

  if (FUSED){
    // acc[po][oo] = ga(ch), acc[po][oo+2] = gb(ch); out = src + ga*sigm(gb)
    const int gm = P1o;
    #pragma unroll
    for (int oo = 0; oo < 2; ++oo){
      int ch = o0 + oo*16 + g*4;
      #pragma unroll
      for (int po = 0; po < 4; ++po){
        int px = hw0 + w*64 + po*16 + cc;
        size_t pb = (size_t)n*HW + px;
        float rr[4];
        #pragma unroll
        for (int i = 0; i < 4; ++i){
          int c = ch + i;
          float r = 0.f;
          if (c < O){
            float ga = acc[po][oo][i]   + bias[c];
            float gb = acc[po][oo+2][i] + bias[O + c];
            float s  = src_ptr(xp, ulp, bp, n, c, gm)[px];
            r = s + ga*sigm(gb);
          }
          rr[i] = r;
        }
        if (EPI == 5){
          uint2 pk;
          pk.x = (uint_t)f2bf(rr[0]) | ((uint_t)f2bf(rr[1])<<16);
          pk.y = (uint_t)f2bf(rr[2]) | ((uint_t)f2bf(rr[3])<<16);
          *(uint2*)((ushort_t*)outv + pb*OP + ch) = pk;
        } else {
          #pragma unroll
          for (int i = 0; i < 4; ++i)
            if (ch + i < O) ((float*)outv)[((size_t)n*O + ch + i)*HW + px] = rr[i];
        }
      }
    }
    return;
  }

  #pragma unroll
  for (int oo = 0; oo < 4; ++oo){
    int ch = o0 + oo*16 + g*4;
    if (ch >= O) continue;
    float b0 = bias[ch];
    float b1 = (ch+1 < O) ? bias[ch+1] : 0.f;
    float b2 = (ch+2 < O) ? bias[ch+2] : 0.f;
    float b3 = (ch+3 < O) ? bias[ch+3] : 0.f;
    #pragma unroll
    for (int po = 0; po < 4; ++po){
      int px = hw0 + w*64 + po*16 + cc;
      size_t pb = (size_t)n*HW + px;
      f32x4 a = acc[po][oo];
      float h0 = a[0]+b0, h1 = a[1]+b1, h2v = a[2]+b2, h3 = a[3]+b3;
      if (EPI == 3){
        float4 av4 = *(const float4*)(accin + pb*AST + ch);
        h0 += av4.x; h1 += av4.y; h2v += av4.z; h3 += av4.w;
      }
      if (EPI == 0){
        *(float4*)((float*)outv + pb*OP + ch) = make_float4(h0, h1, h2v, h3);
      } else if (EPI == 1){
        uint2 pk;
        pk.x = (uint_t)f2bf(h0)  | ((uint_t)f2bf(h1)<<16);
        pk.y = (uint_t)f2bf(h2v) | ((uint_t)f2bf(h3)<<16);
        *(uint2*)((ushort_t*)outv + pb*OP + ch) = pk;
      } else if (EPI == 2 || EPI == 3){
        ushort_t* op = (ushort_t*)outv + pb*OP;
        uint2 pp, pn;
        pp.x = (uint_t)f2bf(elu1(h0))  | ((uint_t)f2bf(elu1(h1))<<16);
        pp.y = (uint_t)f2bf(elu1(h2v)) | ((uint_t)f2bf(elu1(h3))<<16);
        pn.x = (uint_t)f2bf(elu1(-h0))  | ((uint_t)f2bf(elu1(-h1))<<16);
        pn.y = (uint_t)f2bf(elu1(-h2v)) | ((uint_t)f2bf(elu1(-h3))<<16);
        *(uint2*)(op + ch) = pp;
        *(uint2*)(op + P1o + ch) = pn;
      } else {
        ushort_t* ob = (ushort_t*)outv;
        float hv[4] = {h0, h1, h2v, h3};
        #pragma unroll
        for (int i = 0; i < 4; ++i)
          if (ch + i < O) ob[((size_t)n*OP + ch + i)*HW + px] = f2bf(hv[i]);
      }
    }
  }
}

// ---------------- MFMA flash attention, faithful torch-tril softmax ----------------
__global__ __launch_bounds__(64) void k_attn2(const ushort_t* __restrict__ Kp,
    const ushort_t* __restrict__ Qp, const ushort_t* __restrict__ Vc, float* __restrict__ AV){
  const int l = threadIdx.x;
  const int qt = blockIdx.x, n = blockIdx.y;
  const int hi = l >> 5, qcol = l & 31;
  const int qg = qt*32 + qcol;

  s16x8 bq = *(const s16x8*)(Qp + ((size_t)(n*HW + qg))*16 + hi*8);

  f32x16 acc0, acc1, acc2;
  #pragma unroll
  for (int r = 0; r < 16; ++r){ acc0[r]=0.f; acc1[r]=0.f; acc2[r]=0.f; }
  float m = 0.f, S = 0.f;
  const int nkt = qt + 1;

  for (int kt = 0; kt < nkt; ++kt){
    const int j0 = kt*32;
    s16x8 ak = *(const s16x8*)(Kp + ((size_t)(n*HW + j0 + qcol))*16 + hi*8);
    f32x16 zc;
    #pragma unroll
    for (int r = 0; r < 16; ++r) zc[r] = 0.f;
    f32x16 p = __builtin_amdgcn_mfma_f32_32x32x16_bf16(ak, bq, zc, 0, 0, 0);

    float ps[16];
    float tmax = -3.0e38f;
    const bool diag = (kt == qt);
    #pragma unroll
    for (int r = 0; r < 16; ++r){
      int kk = j0 + (r&3) + 8*(r>>2) + 4*hi;
      float sv = p[r];
      if (diag && kk >= qg) sv = -3.0e38f;
      ps[r] = sv;
      tmax = fmaxf(tmax, sv);
    }
    tmax = fmaxf(tmax, __shfl_xor(tmax, 32));
    if (tmax > m + 8.f){
      float f = __expf(m - tmax);
      S *= f;
      #pragma unroll
      for (int r = 0; r < 16; ++r){ acc0[r]*=f; acc1[r]*=f; acc2[r]*=f; }
      m = tmax;
    }
    float pe[16], ts = 0.f;
    #pragma unroll
    for (int r = 0; r < 16; ++r){ pe[r] = __expf(ps[r] - m); ts += pe[r]; }
    S += ts + __shfl_xor(ts, 32);

    uint_t w0 = cvtpk(pe[0],  pe[1]),  w1 = cvtpk(pe[2],  pe[3]);
    uint_t w2 = cvtpk(pe[4],  pe[5]),  w3 = cvtpk(pe[6],  pe[7]);
    uint_t w4 = cvtpk(pe[8],  pe[9]),  w5 = cvtpk(pe[10], pe[11]);
    uint_t w6 = cvtpk(pe[12], pe[13]), w7 = cvtpk(pe[14], pe[15]);
    uint_t o0 = __shfl_xor((int)w0, 32), o1 = __shfl_xor((int)w1, 32);
    uint_t o2 = __shfl_xor((int)w2, 32), o3 = __shfl_xor((int)w3, 32);
    uint_t o4 = __shfl_xor((int)w4, 32), o5 = __shfl_xor((int)w5, 32);
    uint_t o6 = __shfl_xor((int)w6, 32), o7 = __shfl_xor((int)w7, 32);
    u32x4 f0, f1;
    f0.x = hi ? o2 : w0; f0.y = hi ? o3 : w1; f0.z = hi ? w2 : o0; f0.w = hi ? w3 : o1;
    f1.x = hi ? o6 : w4; f1.y = hi ? o7 : w5; f1.z = hi ? w6 : o4; f1.w = hi ? w7 : o5;
    s16x8 pb0 = __builtin_bit_cast(s16x8, f0);
    s16x8 pb1 = __builtin_bit_cast(s16x8, f1);

    const ushort_t* vb = Vc + ((size_t)(n*96 + qcol))*HW + j0 + hi*8;
    s16x8 v00 = *(const s16x8*)(vb);
    s16x8 v01 = *(const s16x8*)(vb + 16);
    s16x8 v10 = *(const s16x8*)(vb + 32*HW);
    s16x8 v11 = *(const s16x8*)(vb + 32*HW + 16);
    s16x8 v20 = *(const s16x8*)(vb + 64*HW);
    s16x8 v21 = *(const s16x8*)(vb + 64*HW + 16);
    acc0 = __builtin_amdgcn_mfma_f32_32x32x16_bf16(v00, pb0, acc0, 0, 0, 0);
    acc0 = __builtin_amdgcn_mfma_f32_32x32x16_bf16(v01, pb1, acc0, 0, 0, 0);
    acc1 = __builtin_amdgcn_mfma_f32_32x32x16_bf16(v10, pb0, acc1, 0, 0, 0);
    acc1 = __builtin_amdgcn_mfma_f32_32x32x16_bf16(v11, pb1, acc1, 0, 0, 0);
    acc2 = __builtin_amdgcn_mfma_f32_32x32x16_bf16(v20, pb0, acc2, 0, 0, 0);
    acc2 = __builtin_amdgcn_mfma_f32_32x32x16_bf16(v21, pb1, acc2, 0, 0, 0);
  }

  float Z = S + (float)(HW - qg)*__expf(-m);
  float inv = 1.f/(S + 1e-7f*Z);
  #pragma unroll
  for (int r = 0; r < 16; ++r){
    int vr = (r&3) + 8*(r>>2) + 4*hi;
    AV[((size_t)(n*80 + vr))*HW + qg]      = acc0[r]*inv;
    AV[((size_t)(n*80 + 32 + vr))*HW + qg] = acc1[r]*inv;
    if (64 + vr < 80) AV[((size_t)(n*80 + 64 + vr))*HW + qg] = acc2[r]*inv;
  }
}

extern "C" void kernel_launch(void* const* d_in, const int* in_sizes, int n_in,
                              void* d_out, int out_size, void* d_ws, size_t ws_size,
                              hipStream_t stream) {
  const float* x    = (const float*)d_in[0];
  const float* ul   = (const float*)d_in[1];
  const float* bb   = (const float*)d_in[2];
  const float* gkWi = (const float*)d_in[3];  const float* gkbi = (const float*)d_in[4];
  const float* gkWo = (const float*)d_in[5];  const float* gkbo = (const float*)d_in[6];
  const float* gqWi = (const float*)d_in[7];  const float* gqbi = (const float*)d_in[8];
  const float* gqWo = (const float*)d_in[9];  const float* gqbo = (const float*)d_in[10];
  const float* gvWi = (const float*)d_in[11]; const float* gvbi = (const float*)d_in[12];
  const float* gvWo = (const float*)d_in[13]; const float* gvbo = (const float*)d_in[14];
  const float* nkW  = (const float*)d_in[15]; const float* nkb  = (const float*)d_in[16];
  const float* nqW  = (const float*)d_in[17]; const float* nqb  = (const float*)d_in[18];
  const float* nvW  = (const float*)d_in[19]; const float* nvb  = (const float*)d_in[20];
  const float* goWi = (const float*)d_in[21]; const float* gobi = (const float*)d_in[22];
  const float* goWs = (const float*)d_in[23]; const float* gobs = (const float*)d_in[24];
  const float* goWo = (const float*)d_in[25]; const float* gobo = (const float*)d_in[26];
  float* outp = (float*)d_out;
  char* wsb = (char*)d_ws;

  ushort_t* R0 = (ushort_t*)(wsb + 0);           // ce_xulb / ce_ulb ; later h1o fp32
  ushort_t* R1 = (ushort_t*)(wsb + 23068672);    // ce_h1 ; later ce_ul
  ushort_t* R2 = (ushort_t*)(wsb + 46137344);    // later ce of goWs-out
  ushort_t* R3 = (ushort_t*)(wsb + 71303168);    // grn-out (stride 192) / ce_attv
  ushort_t* Kp = (ushort_t*)(wsb + 83886080);    // [32][1024][16] bf16
  ushort_t* Qp = (ushort_t*)(wsb + 84934656);
  ushort_t* Vc = (ushort_t*)(wsb + 85983232);    // [32][96][1024] bf16 chan-major
  float*    AV = (float*)   (wsb + 92274688);    // [32][80][1024] fp32 chan-major
  ushort_t* Wb = (ushort_t*)(wsb + 102760448);   // bf16 weights

  // weight descs: gkWi gkWo nkW gqWi gqWo nqW gvWi gvWo nvW goWi goWs goWo
  static const int dDst[12]  = {0,67584,202752,215040,282624,417792,430080,497664,632832,657408,718848,749568};
  static const int dO[12]    = {169,338,16,166,332,16,169,338,80,160,160,320};
  static const int dKt[12]   = {338,338,169,332,332,166,338,338,169,320,160,320};
  static const int dK1[12]   = {169,169,169,166,166,166,169,169,169,160,80,320};
  static const int dP1[12]   = {176,176,9999,176,176,9999,176,176,9999,160,80,9999};
  static const int dOp[12]   = {192,384,64,192,384,64,192,384,128,192,192,384};
  static const int dKp[12]   = {352,352,192,352,352,192,352,352,192,320,160,320};
  static const int dOh[12]   = {0,169,0,0,166,0,0,169,0,0,0,160};   // fused Wo paired layout

  SPtrs sp; WCfg wc;
  const float* srcs[12] = {gkWi,gkWo,nkW,gqWi,gqWo,nqW,gvWi,gvWo,nvW,goWi,goWs,goWo};
  for (int i = 0; i < 12; ++i){
    sp.p[i] = srcs[i];
    wc.dst[i]=dDst[i]; wc.O[i]=dO[i]; wc.Kt[i]=dKt[i]; wc.K1[i]=dK1[i];
    wc.P1[i]=dP1[i]; wc.Opad[i]=dOp[i]; wc.Kpad[i]=dKp[i]; wc.Oh[i]=dOh[i];
  }

  dim3 b256(256), b64t(64);
  k_wconv<<<dim3(32,12), b256, 0, stream>>>(sp, wc, Wb);

#define GMM2(EPI, DI, GY, BIASP, ACT, ACCIN, OUT, O_, CP_, OP_, P1O_, AST_) \
  k_gmm2<EPI><<<dim3(128, GY), b256, 0, stream>>>( \
    Wb + dDst[DI], BIASP, (const ushort_t*)(ACT), ACCIN, OUT, x, ul, bb, \
    O_, dKp[DI], CP_, OP_, P1O_, AST_)

  // ---- keys path ----
  k_act<0><<<dim3(128,22), b256, 0, stream>>>(x, ul, bb, nullptr, R0, 169, 176, 352);
  GMM2(2, 0, 3, gkbi, R0, nullptr, R1, 169, 352, 352, 176, 0);
  GMM2(5, 1, 6, gkbo, R1, nullptr, R3, 169, 352, 192, 0, 0);    // fused res2, gm=0
  GMM2(1, 2, 1, nkb, R3, nullptr, Kp, 16, 192, 16, 0, 0);

  // ---- values path ----
  GMM2(2, 6, 3, gvbi, R0, nullptr, R1, 169, 352, 352, 176, 0);
  GMM2(5, 7, 6, gvbo, R1, nullptr, R3, 169, 352, 192, 0, 0);    // fused res2, gm=0
  GMM2(4, 8, 2, nvb, R3, nullptr, Vc, 80, 192, 96, 0, 0);

  // ---- queries path ----
  k_act<1><<<dim3(128,22), b256, 0, stream>>>(x, ul, bb, nullptr, R0, 166, 176, 352);
  GMM2(2, 3, 3, gqbi, R0, nullptr, R1, 166, 352, 352, 176, 0);
  GMM2(5, 4, 6, gqbo, R1, nullptr, R3, 166, 352, 192, 1, 0);    // fused res2, gm=1
  GMM2(1, 5, 1, nqb, R3, nullptr, Qp, 16, 192, 16, 0, 0);

  // ---- attention ----
  k_attn2<<<dim3(32, 32), b64t, 0, stream>>>(Kp, Qp, Vc, AV);

  // ---- output grn ----
  k_act<2><<<dim3(128,20), b256, 0, stream>>>(x, ul, bb, nullptr, R1, 160, 160, 320);
  k_act<3><<<dim3(128,10), b256, 0, stream>>>(x, ul, bb, AV, R3, 80, 80, 160);
  GMM2(0, 9, 3, gobi, R1, nullptr, (float*)R0, 160, 320, 160, 0, 0);
  GMM2(3, 10, 3, gobs, R3, (const float*)R0, R2, 160, 160, 320, 160, 160);
  GMM2(6, 11, 5, gobo, R2, nullptr, outp, 160, 320, 0, 2, 0);   // fused res2 final, gm=2
}

// Round 6
// 445.188 us; speedup vs baseline: 12.2152x; 1.0648x over previous
//
#include <hip/hip_runtime.h>
#include <cstddef>
#include <cstdint>

#define HW 1024
#define NBATCH 32

typedef unsigned short ushort_t;
typedef unsigned int uint_t;
typedef short s16x8 __attribute__((ext_vector_type(8)));
typedef float f32x4 __attribute__((ext_vector_type(4)));
typedef float f32x16 __attribute__((ext_vector_type(16)));
typedef unsigned int u32x4 __attribute__((ext_vector_type(4)));

__device__ __forceinline__ float elu1(float z){ return z > 0.f ? z : __expf(z) - 1.f; }
__device__ __forceinline__ float sigm(float z){ return 1.f/(1.f+__expf(-z)); }
__device__ __forceinline__ ushort_t f2bf(float f){
  uint_t u = __builtin_bit_cast(uint_t, f);
  u += 0x7FFFu + ((u >> 16) & 1u);
  return (ushort_t)(u >> 16);
}
__device__ __forceinline__ float bf2f(ushort_t h){
  uint_t u = ((uint_t)h) << 16;
  return __builtin_bit_cast(float, u);
}
__device__ __forceinline__ uint_t cvtpk(float lo, float hi){
  uint_t r;
  asm("v_cvt_pk_bf16_f32 %0, %1, %2" : "=v"(r) : "v"(lo), "v"(hi));
  return r;
}
__device__ __forceinline__ void gload_lds16(const void* g, void* l){
  __builtin_amdgcn_global_load_lds((const __attribute__((address_space(1))) unsigned int*)g,
                                   (__attribute__((address_space(3))) unsigned int*)l, 16, 0, 0);
}

// gm: 0 = concat(x[3],ul[160],b[6]) (169 ch), 1 = concat(ul,b) (166), 2 = ul (160)
__device__ __forceinline__ const float* src_ptr(const float* x, const float* ul, const float* b,
                                                int n, int c, int gm){
  if (gm == 0){
    if (c < 3)   return x  + ((size_t)n*3   + c)*HW;
    if (c < 163) return ul + ((size_t)n*160 + (c-3))*HW;
    return b + ((size_t)n*6 + (c-163))*HW;
  } else if (gm == 1){
    if (c < 160) return ul + ((size_t)n*160 + c)*HW;
    return b + ((size_t)n*6 + (c-160))*HW;
  }
  return ul + ((size_t)n*160 + c)*HW;
}

// ---------------- concat_elu -> bf16 pixel-major; grid (pxblocks, P1/8) ----------------
template<int GM>
__global__ void k_act(const float* __restrict__ x, const float* __restrict__ ul,
                      const float* __restrict__ b,
                      ushort_t* __restrict__ out, int Cb, int P1, int CP){
  int pxg = blockIdx.x*256 + threadIdx.x;
  int n = pxg >> 10, hw = pxg & 1023;
  int c8 = blockIdx.y*8;
  ushort_t* orow = out + (size_t)pxg * CP;
  ushort_t pbuf[8], nbuf[8];
  #pragma unroll
  for (int j = 0; j < 8; ++j){
    int c = c8 + j;
    float s = 0.f;
    if (c < Cb) s = src_ptr(x, ul, b, n, c, GM)[hw];
    pbuf[j] = f2bf(elu1(s));
    nbuf[j] = f2bf(elu1(-s));
  }
  uint4 up, un;
  up.x = (uint_t)pbuf[0] | ((uint_t)pbuf[1]<<16);
  up.y = (uint_t)pbuf[2] | ((uint_t)pbuf[3]<<16);
  up.z = (uint_t)pbuf[4] | ((uint_t)pbuf[5]<<16);
  up.w = (uint_t)pbuf[6] | ((uint_t)pbuf[7]<<16);
  un.x = (uint_t)nbuf[0] | ((uint_t)nbuf[1]<<16);
  un.y = (uint_t)nbuf[2] | ((uint_t)nbuf[3]<<16);
  un.z = (uint_t)nbuf[4] | ((uint_t)nbuf[5]<<16);
  un.w = (uint_t)nbuf[6] | ((uint_t)nbuf[7]<<16);
  *(uint4*)(orow + c8)      = up;
  *(uint4*)(orow + P1 + c8) = un;
}

// ---------------- weight pre-convert ----------------
// fp32 [O][Kt] -> padded bf16 [Opad][Kpad]; col map kk<K1->kk, [P1,P1+K2)->K1+kk-P1, else 0.
// Oh>0 (fused-res2 Wo): dst row o<192 -> src o (valid o<Oh); o>=192 -> src Oh+(o-192).
// d==9: merged goWi|goWs: cols<320 from p[9] (goWi[160][320]), cols>=320 from p[11] (goWs[160][160]).
struct SPtrs { const float* p[12]; };
struct WCfg  { int dst[12], O[12], Kt[12], K1[12], P1[12], Opad[12], Kpad[12], Oh[12]; };

__global__ void k_wconv(SPtrs sp, WCfg c, ushort_t* __restrict__ Wb){
  int d = blockIdx.y;
  int O = c.O[d], Kt = c.Kt[d], K1 = c.K1[d], P1 = c.P1[d], Op = c.Opad[d], Kp = c.Kpad[d], Oh = c.Oh[d];
  ushort_t* dst = Wb + c.dst[d];
  int total = Op*Kp;
  if (d == 9){
    const float* wi = sp.p[9];
    const float* ws = sp.p[11];
    for (int i = blockIdx.x*256 + threadIdx.x; i < total; i += 32*256){
      int o = i / Kp, kk = i - o*Kp;
      float v = 0.f;
      if (o < O) v = (kk < 320) ? wi[(size_t)o*320 + kk] : ws[(size_t)o*160 + (kk - 320)];
      dst[i] = f2bf(v);
    }
    return;
  }
  const float* src = sp.p[d];
  int K2 = Kt - K1;
  for (int i = blockIdx.x*256 + threadIdx.x; i < total; i += 32*256){
    int o = i / Kp, kk = i - o*Kp;
    int k = (kk < K1) ? kk : ((kk >= P1 && kk < P1 + K2) ? (K1 + kk - P1) : -1);
    int so; bool rv;
    if (Oh > 0){
      if (o < 192){ so = o; rv = (o < Oh); }
      else        { so = Oh + (o - 192); rv = ((o - 192) < Oh); }
    } else { so = o; rv = (o < O); }
    float v = (rv && k >= 0) ? src[(size_t)so*Kt + k] : 0.f;
    dst[i] = f2bf(v);
  }
}

// ---------------- MFMA GEMM: 256px x 64o tile, A from L2->regs, B wave-private LDS ----------------
// EPI: 1 bf16 pixel-major(OP); 2 ce bf16 (neg at P1o, stride OP); 4 bf16 channel-major (OP rows/n);
//      5 fused grn-residual -> bf16 pixel-major(OP) [gm=P1o, paired Wo]; 6 fused -> fp32 ch-major out;
//      7 = EPI2 + bias2 (merged goWi|goWs); 8 = EPI2 dual-output (rows>=192 -> outv2, bias2)
template<int EPI>
__global__ __launch_bounds__(256) void k_gmm2(const ushort_t* __restrict__ Wb,
    const float* __restrict__ bias, const float* __restrict__ bias2,
    const ushort_t* __restrict__ act, void* __restrict__ outv, void* __restrict__ outv2,
    const float* __restrict__ xp, const float* __restrict__ ulp, const float* __restrict__ bp,
    int O, int Kpad, int CP, int OP, int P1o)
{
  __shared__ ushort_t Blds[4][2][2048];   // per-wave 2x4KB dbuf
  const int tid = threadIdx.x;
  const int w = tid >> 6, l = tid & 63;
  const int n = blockIdx.x >> 2, hw0 = (blockIdx.x & 3)*256;
  const bool FUSED = (EPI == 5 || EPI == 6);
  const int o0 = blockIdx.y*(FUSED ? 32 : 64);

  const ushort_t* actw = act + (size_t)(n*HW + hw0 + w*64)*CP;
  const ushort_t* Wbo  = Wb + (size_t)o0*Kpad;
  const size_t r2off = FUSED ? (size_t)192*Kpad : (size_t)32*Kpad;

#define STAGE2(bufi, ktv) do { \
    int cl_ = (l & 3) ^ ((l >> 4) & 2); \
    _Pragma("unroll") \
    for (int s_ = 0; s_ < 4; ++s_){ \
      const ushort_t* g_ = actw + (size_t)(s_*16 + (l>>2))*CP + (ktv)*32 + cl_*8; \
      gload_lds16(g_, &Blds[w][bufi][s_*512]); \
    } \
  } while(0)

  f32x4 acc[4][4];
  #pragma unroll
  for (int i = 0; i < 4; ++i)
    #pragma unroll
    for (int j = 0; j < 4; ++j) acc[i][j] = (f32x4){0.f,0.f,0.f,0.f};

  const int NT = Kpad >> 5;
  STAGE2(0, 0);
  for (int kt = 0; kt < NT; ++kt){
    int cur = kt & 1;
    const ushort_t* Ab = Wbo + (size_t)(l&15)*Kpad + kt*32 + (l>>4)*8;
    s16x8 a0 = *(const s16x8*)(Ab);
    s16x8 a1 = *(const s16x8*)(Ab + 16*Kpad);
    s16x8 a2 = *(const s16x8*)(Ab + r2off);
    s16x8 a3 = *(const s16x8*)(Ab + r2off + 16*Kpad);
    if (kt + 1 < NT) STAGE2(cur^1, kt+1);
    asm volatile("s_waitcnt vmcnt(4)" ::: "memory");
    const ushort_t* Bb = &Blds[w][cur][0];
    const int chp = ((l>>4) ^ ((l>>2)&2))*8;
    #pragma unroll
    for (int po = 0; po < 4; ++po){
      s16x8 bv = *(const s16x8*)(Bb + po*512 + (l&15)*32 + chp);
      acc[po][0] = __builtin_amdgcn_mfma_f32_16x16x32_bf16(a0, bv, acc[po][0], 0, 0, 0);
      acc[po][1] = __builtin_amdgcn_mfma_f32_16x16x32_bf16(a1, bv, acc[po][1], 0, 0, 0);
      acc[po][2] = __builtin_amdgcn_mfma_f32_16x16x32_bf16(a2, bv, acc[po][2], 0, 0, 0);
      acc[po][3] = __builtin_amdgcn_mfma_f32_16x16x32_bf16(a3, bv, acc[po][3], 0, 0, 0);
    }
  }
#undef STAGE2

  // D frag: col = l&15 (px), row = (l>>4)*4 + reg
  const int g = l >> 4, cc = l & 15;

  if (FUSED){
    // acc[po][oo] = ga(ch), acc[po][oo+2] = gb(ch); out = src + ga*sigm(gb)
    const int gm = P1o;
    #pragma unroll
    for (int oo = 0; oo < 2; ++oo){
      int ch = o0 + oo*16 + g*4;
      #pragma unroll
      for (int po = 0; po < 4; ++po){
        int px = hw0 + w*64 + po*16 + cc;
        size_t pb = (size_t)n*HW + px;
        float rr[4];
        #pragma unroll
        for (int i = 0; i < 4; ++i){
          int c = ch + i;
          float r = 0.f;
          if (c < O){
            float ga = acc[po][oo][i]   + bias[c];
            float gb = acc[po][oo+2][i] + bias[O + c];
            float s  = src_ptr(xp, ulp, bp, n, c, gm)[px];
            r = s + ga*sigm(gb);
          }
          rr[i] = r;
        }
        if (EPI == 5){
          uint2 pk;
          pk.x = (uint_t)f2bf(rr[0]) | ((uint_t)f2bf(rr[1])<<16);
          pk.y = (uint_t)f2bf(rr[2]) | ((uint_t)f2bf(rr[3])<<16);
          *(uint2*)((ushort_t*)outv + pb*OP + ch) = pk;
        } else {
          #pragma unroll
          for (int i = 0; i < 4; ++i)
            if (ch + i < O) ((float*)outv)[((size_t)n*O + ch + i)*HW + px] = rr[i];
        }
      }
    }
    return;
  }

  #pragma unroll
  for (int oo = 0; oo < 4; ++oo){
    int ch = o0 + oo*16 + g*4;
    int c = ch;
    const float* bsp = bias;
    ushort_t* oP = (ushort_t*)outv;
    if (EPI == 8 && ch >= 192){ c = ch - 192; bsp = bias2; oP = (ushort_t*)outv2; }
    if (c >= O) continue;
    float b0 = bsp[c];
    float b1 = (c+1 < O) ? bsp[c+1] : 0.f;
    float b2 = (c+2 < O) ? bsp[c+2] : 0.f;
    float b3 = (c+3 < O) ? bsp[c+3] : 0.f;
    if (EPI == 7){
      b0 += bias2[c];
      if (c+1 < O) b1 += bias2[c+1];
      if (c+2 < O) b2 += bias2[c+2];
      if (c+3 < O) b3 += bias2[c+3];
    }
    #pragma unroll
    for (int po = 0; po < 4; ++po){
      int px = hw0 + w*64 + po*16 + cc;
      size_t pb = (size_t)n*HW + px;
      f32x4 a = acc[po][oo];
      float h0 = a[0]+b0, h1 = a[1]+b1, h2v = a[2]+b2, h3 = a[3]+b3;
      if (EPI == 1){
        uint2 pk;
        pk.x = (uint_t)f2bf(h0)  | ((uint_t)f2bf(h1)<<16);
        pk.y = (uint_t)f2bf(h2v) | ((uint_t)f2bf(h3)<<16);
        *(uint2*)(oP + pb*OP + c) = pk;
      } else if (EPI == 2 || EPI == 7 || EPI == 8){
        ushort_t* op = oP + pb*OP;
        uint2 pp, pn;
        pp.x = (uint_t)f2bf(elu1(h0))  | ((uint_t)f2bf(elu1(h1))<<16);
        pp.y = (uint_t)f2bf(elu1(h2v)) | ((uint_t)f2bf(elu1(h3))<<16);
        pn.x = (uint_t)f2bf(elu1(-h0))  | ((uint_t)f2bf(elu1(-h1))<<16);
        pn.y = (uint_t)f2bf(elu1(-h2v)) | ((uint_t)f2bf(elu1(-h3))<<16);
        *(uint2*)(op + c) = pp;
        *(uint2*)(op + P1o + c) = pn;
      } else {  // EPI 4: bf16 channel-major
        float hv[4] = {h0, h1, h2v, h3};
        #pragma unroll
        for (int i = 0; i < 4; ++i)
          if (c + i < O) oP[((size_t)n*OP + c + i)*HW + px] = f2bf(hv[i]);
      }
    }
  }
}

// ---------------- MFMA flash attention; writes ce(att_v) bf16 into merged act buffer ----------------
__global__ __launch_bounds__(64) void k_attn2(const ushort_t* __restrict__ Kp,
    const ushort_t* __restrict__ Qp, const ushort_t* __restrict__ Vc, ushort_t* __restrict__ Mb){
  const int l = threadIdx.x;
  const int qt = blockIdx.x, n = blockIdx.y;
  const int hi = l >> 5, qcol = l & 31;
  const int qg = qt*32 + qcol;

  s16x8 bq = *(const s16x8*)(Qp + ((size_t)(n*HW + qg))*16 + hi*8);

  f32x16 acc0, acc1, acc2;
  #pragma unroll
  for (int r = 0; r < 16; ++r){ acc0[r]=0.f; acc1[r]=0.f; acc2[r]=0.f; }
  float m = 0.f, S = 0.f;
  const int nkt = qt + 1;

  for (int kt = 0; kt < nkt; ++kt){
    const int j0 = kt*32;
    s16x8 ak = *(const s16x8*)(Kp + ((size_t)(n*HW + j0 + qcol))*16 + hi*8);
    f32x16 zc;
    #pragma unroll
    for (int r = 0; r < 16; ++r) zc[r] = 0.f;
    f32x16 p = __builtin_amdgcn_mfma_f32_32x32x16_bf16(ak, bq, zc, 0, 0, 0);

    float ps[16];
    float tmax = -3.0e38f;
    const bool diag = (kt == qt);
    #pragma unroll
    for (int r = 0; r < 16; ++r){
      int kk = j0 + (r&3) + 8*(r>>2) + 4*hi;
      float sv = p[r];
      if (diag && kk >= qg) sv = -3.0e38f;
      ps[r] = sv;
      tmax = fmaxf(tmax, sv);
    }
    tmax = fmaxf(tmax, __shfl_xor(tmax, 32));
    if (tmax > m + 8.f){
      float f = __expf(m - tmax);
      S *= f;
      #pragma unroll
      for (int r = 0; r < 16; ++r){ acc0[r]*=f; acc1[r]*=f; acc2[r]*=f; }
      m = tmax;
    }
    float pe[16], ts = 0.f;
    #pragma unroll
    for (int r = 0; r < 16; ++r){ pe[r] = __expf(ps[r] - m); ts += pe[r]; }
    S += ts + __shfl_xor(ts, 32);

    uint_t w0 = cvtpk(pe[0],  pe[1]),  w1 = cvtpk(pe[2],  pe[3]);
    uint_t w2 = cvtpk(pe[4],  pe[5]),  w3 = cvtpk(pe[6],  pe[7]);
    uint_t w4 = cvtpk(pe[8],  pe[9]),  w5 = cvtpk(pe[10], pe[11]);
    uint_t w6 = cvtpk(pe[12], pe[13]), w7 = cvtpk(pe[14], pe[15]);
    uint_t o0 = __shfl_xor((int)w0, 32), o1 = __shfl_xor((int)w1, 32);
    uint_t o2 = __shfl_xor((int)w2, 32), o3 = __shfl_xor((int)w3, 32);
    uint_t o4 = __shfl_xor((int)w4, 32), o5 = __shfl_xor((int)w5, 32);
    uint_t o6 = __shfl_xor((int)w6, 32), o7 = __shfl_xor((int)w7, 32);
    u32x4 f0, f1;
    f0.x = hi ? o2 : w0; f0.y = hi ? o3 : w1; f0.z = hi ? w2 : o0; f0.w = hi ? w3 : o1;
    f1.x = hi ? o6 : w4; f1.y = hi ? o7 : w5; f1.z = hi ? w6 : o4; f1.w = hi ? w7 : o5;
    s16x8 pb0 = __builtin_bit_cast(s16x8, f0);
    s16x8 pb1 = __builtin_bit_cast(s16x8, f1);

    const ushort_t* vb = Vc + ((size_t)(n*96 + qcol))*HW + j0 + hi*8;
    s16x8 v00 = *(const s16x8*)(vb);
    s16x8 v01 = *(const s16x8*)(vb + 16);
    s16x8 v10 = *(const s16x8*)(vb + 32*HW);
    s16x8 v11 = *(const s16x8*)(vb + 32*HW + 16);
    s16x8 v20 = *(const s16x8*)(vb + 64*HW);
    s16x8 v21 = *(const s16x8*)(vb + 64*HW + 16);
    acc0 = __builtin_amdgcn_mfma_f32_32x32x16_bf16(v00, pb0, acc0, 0, 0, 0);
    acc0 = __builtin_amdgcn_mfma_f32_32x32x16_bf16(v01, pb1, acc0, 0, 0, 0);
    acc1 = __builtin_amdgcn_mfma_f32_32x32x16_bf16(v10, pb0, acc1, 0, 0, 0);
    acc1 = __builtin_amdgcn_mfma_f32_32x32x16_bf16(v11, pb1, acc1, 0, 0, 0);
    acc2 = __builtin_amdgcn_mfma_f32_32x32x16_bf16(v20, pb0, acc2, 0, 0, 0);
    acc2 = __builtin_amdgcn_mfma_f32_32x32x16_bf16(v21, pb1, acc2, 0, 0, 0);
  }

  float Z = S + (float)(HW - qg)*__expf(-m);
  float inv = 1.f/(S + 1e-7f*Z);
  // write ce(att_v) into merged buffer cols [320,480): pos at 320+v, neg at 400+v
  ushort_t* mrow = Mb + (size_t)(n*HW + qg)*480 + 320;
  #pragma unroll
  for (int rg = 0; rg < 4; ++rg){
    int vb = 8*rg + 4*hi;
    float a0v[4], a1v[4];
    #pragma unroll
    for (int i = 0; i < 4; ++i){ a0v[i] = acc0[4*rg+i]*inv; a1v[i] = acc1[4*rg+i]*inv; }
    uint2 pp, pn;
    pp.x = (uint_t)f2bf(elu1(a0v[0]))  | ((uint_t)f2bf(elu1(a0v[1]))<<16);
    pp.y = (uint_t)f2bf(elu1(a0v[2]))  | ((uint_t)f2bf(elu1(a0v[3]))<<16);
    pn.x = (uint_t)f2bf(elu1(-a0v[0])) | ((uint_t)f2bf(elu1(-a0v[1]))<<16);
    pn.y = (uint_t)f2bf(elu1(-a0v[2])) | ((uint_t)f2bf(elu1(-a0v[3]))<<16);
    *(uint2*)(mrow + vb) = pp;
    *(uint2*)(mrow + 80 + vb) = pn;
    pp.x = (uint_t)f2bf(elu1(a1v[0]))  | ((uint_t)f2bf(elu1(a1v[1]))<<16);
    pp.y = (uint_t)f2bf(elu1(a1v[2]))  | ((uint_t)f2bf(elu1(a1v[3]))<<16);
    pn.x = (uint_t)f2bf(elu1(-a1v[0])) | ((uint_t)f2bf(elu1(-a1v[1]))<<16);
    pn.y = (uint_t)f2bf(elu1(-a1v[2])) | ((uint_t)f2bf(elu1(-a1v[3]))<<16);
    *(uint2*)(mrow + 32 + vb) = pp;
    *(uint2*)(mrow + 112 + vb) = pn;
    if (rg < 2){
      float a2v[4];
      #pragma unroll
      for (int i = 0; i < 4; ++i) a2v[i] = acc2[4*rg+i]*inv;
      pp.x = (uint_t)f2bf(elu1(a2v[0]))  | ((uint_t)f2bf(elu1(a2v[1]))<<16);
      pp.y = (uint_t)f2bf(elu1(a2v[2]))  | ((uint_t)f2bf(elu1(a2v[3]))<<16);
      pn.x = (uint_t)f2bf(elu1(-a2v[0])) | ((uint_t)f2bf(elu1(-a2v[1]))<<16);
      pn.y = (uint_t)f2bf(elu1(-a2v[2])) | ((uint_t)f2bf(elu1(-a2v[3]))<<16);
      *(uint2*)(mrow + 64 + vb) = pp;
      *(uint2*)(mrow + 144 + vb) = pn;
    }
  }
}

extern "C" void kernel_launch(void* const* d_in, const int* in_sizes, int n_in,
                              void* d_out, int out_size, void* d_ws, size_t ws_size,
                              hipStream_t stream) {
  const float* x    = (const float*)d_in[0];
  const float* ul   = (const float*)d_in[1];
  const float* bb   = (const float*)d_in[2];
  const float* gkWi = (const float*)d_in[3];  const float* gkbi = (const float*)d_in[4];
  const float* gkWo = (const float*)d_in[5];  const float* gkbo = (const float*)d_in[6];
  const float* gqWi = (const float*)d_in[7];  const float* gqbi = (const float*)d_in[8];
  const float* gqWo = (const float*)d_in[9];  const float* gqbo = (const float*)d_in[10];
  const float* gvWi = (const float*)d_in[11]; const float* gvbi = (const float*)d_in[12];
  const float* gvWo = (const float*)d_in[13]; const float* gvbo = (const float*)d_in[14];
  const float* nkW  = (const float*)d_in[15]; const float* nkb  = (const float*)d_in[16];
  const float* nqW  = (const float*)d_in[17]; const float* nqb  = (const float*)d_in[18];
  const float* nvW  = (const float*)d_in[19]; const float* nvb  = (const float*)d_in[20];
  const float* goWi = (const float*)d_in[21]; const float* gobi = (const float*)d_in[22];
  const float* goWs = (const float*)d_in[23]; const float* gobs = (const float*)d_in[24];
  const float* goWo = (const float*)d_in[25]; const float* gobo = (const float*)d_in[26];
  float* outp = (float*)d_out;
  char* wsb = (char*)d_ws;

  ushort_t* R0  = (ushort_t*)(wsb + 0);           // ce_xulb / ce_ulb (CP 352)
  ushort_t* R1k = (ushort_t*)(wsb + 23068672);    // Wi-K out / Wi-Q out (CP 352)
  ushort_t* R1v = (ushort_t*)(wsb + 46137344);    // Wi-V out (CP 352)
  ushort_t* R3  = (ushort_t*)(wsb + 69206016);    // grn-out (CP 192), reused per path
  ushort_t* Kp  = (ushort_t*)(wsb + 81788928);    // [32][1024][16] bf16
  ushort_t* Qp  = (ushort_t*)(wsb + 82837504);
  ushort_t* Vc  = (ushort_t*)(wsb + 83886080);    // [32][96][1024] bf16 chan-major
  ushort_t* M   = (ushort_t*)(wsb + 90177536);    // merged act: ce_ul [0,320) + ce_attv [320,480)
  ushort_t* R2  = (ushort_t*)(wsb + 121634816);   // ce of goWiWs out (CP 320)
  ushort_t* Wb  = (ushort_t*)(wsb + 142606336);   // bf16 weights

  // descs: 0 gkWi, 1 gvWi, 2 gkWo, 3 gvWo, 4 nkW, 5 nvW, 6 gqWi, 7 gqWo, 8 nqW, 9 goWiWs, 10 goWo
  static const int dDst[12] = {0,67584,135168,270336,405504,417792,442368,509952,645120,657408,749568,0};
  static const int dO[12]   = {169,169,338,338,16,80,166,332,16,160,320,0};
  static const int dKt[12]  = {338,338,338,338,169,169,332,332,166,0,320,0};
  static const int dK1[12]  = {169,169,169,169,169,169,166,166,166,0,320,0};
  static const int dP1[12]  = {176,176,176,176,9999,9999,176,176,9999,0,9999,0};
  static const int dOp[12]  = {192,192,384,384,64,128,192,384,64,192,384,0};
  static const int dKp[12]  = {352,352,352,352,192,192,352,352,192,480,320,0};
  static const int dOh[12]  = {0,0,169,169,0,0,0,166,0,0,160,0};

  SPtrs sp; WCfg wc;
  const float* srcs[12] = {gkWi,gvWi,gkWo,gvWo,nkW,nvW,gqWi,gqWo,nqW,goWi,goWo,goWs};
  for (int i = 0; i < 12; ++i){
    sp.p[i] = srcs[i];
    wc.dst[i]=dDst[i]; wc.O[i]=dO[i]; wc.Kt[i]=dKt[i]; wc.K1[i]=dK1[i];
    wc.P1[i]=dP1[i]; wc.Opad[i]=dOp[i]; wc.Kpad[i]=dKp[i]; wc.Oh[i]=dOh[i];
  }

  dim3 b256(256), b64t(64);
  k_wconv<<<dim3(32,11), b256, 0, stream>>>(sp, wc, Wb);

#define GMM2(EPI, DI, GY, B1, B2, ACT, OUT, OUT2, O_, CP_, OP_, P1O_) \
  k_gmm2<EPI><<<dim3(128, GY), b256, 0, stream>>>( \
    Wb + dDst[DI], B1, B2, (const ushort_t*)(ACT), OUT, OUT2, x, ul, bb, \
    O_, dKp[DI], CP_, OP_, P1O_)

  // ---- keys + values shared input ----
  k_act<0><<<dim3(128,22), b256, 0, stream>>>(x, ul, bb, R0, 169, 176, 352);
  GMM2(8, 0, 6, gkbi, gvbi, R0, R1k, R1v, 169, 352, 352, 176);   // merged gkWi|gvWi
  GMM2(5, 2, 6, gkbo, nullptr, R1k, R3, nullptr, 169, 352, 192, 0);
  GMM2(1, 4, 1, nkb, nullptr, R3, Kp, nullptr, 16, 192, 16, 0);
  GMM2(5, 3, 6, gvbo, nullptr, R1v, R3, nullptr, 169, 352, 192, 0);
  GMM2(4, 5, 2, nvb, nullptr, R3, Vc, nullptr, 80, 192, 96, 0);

  // ---- queries path ----
  k_act<1><<<dim3(128,22), b256, 0, stream>>>(x, ul, bb, R0, 166, 176, 352);
  GMM2(2, 6, 3, gqbi, nullptr, R0, R1k, nullptr, 166, 352, 352, 176);
  GMM2(5, 7, 6, gqbo, nullptr, R1k, R3, nullptr, 166, 352, 192, 1);
  GMM2(1, 8, 1, nqb, nullptr, R3, Qp, nullptr, 16, 192, 16, 0);

  // ---- ce(ul) into merged buffer (cols [0,320)) ----
  k_act<2><<<dim3(128,20), b256, 0, stream>>>(x, ul, bb, M, 160, 160, 480);

  // ---- attention: writes ce(att_v) into merged buffer (cols [320,480)) ----
  k_attn2<<<dim3(32, 32), b64t, 0, stream>>>(Kp, Qp, Vc, M);

  // ---- output grn ----
  GMM2(7, 9, 3, gobi, gobs, M, R2, nullptr, 160, 480, 320, 160);  // merged goWi|goWs + ce
  GMM2(6, 10, 5, gobo, nullptr, R2, outp, nullptr, 160, 320, 0, 2); // fused res2 final, gm=2
}